// Round 13
// baseline (1013.642 us; speedup 1.0000x reference)
//
#include <hip/hip_runtime.h>
#include <hip/hip_bf16.h>

// ---- problem constants ----
constexpr int EN   = 100000;  // edges
constexpr int NN   = 10000;   // nodes
constexpr int DEPTH = 6;
constexpr int NSEG = 100;
constexpr int LP   = 40;      // padded LDS row stride (u16)

typedef unsigned short u16;
typedef __bf16 bf16x8 __attribute__((ext_vector_type(8)));
typedef float  f32x4  __attribute__((ext_vector_type(4)));

__device__ inline float wred_max(float v){
#pragma unroll
  for (int o = 32; o > 0; o >>= 1) v = fmaxf(v, __shfl_xor(v, o, 64));
  return v;
}
__device__ inline float wred_sum(float v){
#pragma unroll
  for (int o = 32; o > 0; o >>= 1) v += __shfl_xor(v, o, 64);
  return v;
}
__device__ inline float siluf(float x){ return x / (1.f + __expf(-x)); }
__device__ inline float fast_tanh(float x){
  float e = __expf(2.f * x);
  return 1.f - 2.f / (e + 1.f);
}
// fast RNE float->bf16 (finite inputs only; bitwise identical to RNE).
__device__ inline u16 f2bf(float x){
  unsigned u = __float_as_uint(x);
  u = u + 0x7FFFu + ((u >> 16) & 1u);
  return (u16)(u >> 16);
}
__device__ inline float bf2f(u16 u){
  union { float f; unsigned int ui; } v; v.ui = ((unsigned int)u) << 16; return v.f;
}
__device__ inline bf16x8 ldg_bf8(const u16* p){
  return *reinterpret_cast<const bf16x8*>(p);
}

// ---- dst histogram ----
__global__ __launch_bounds__(256) void count_k(const int* __restrict__ edges,
                                               int* __restrict__ counts){
  int e = blockIdx.x * 256 + threadIdx.x;
  if (e >= EN) return;
  atomicAdd(&counts[edges[2*e]], 1);
}

// ---- exclusive scan of counts -> offsets (single block) ----
__global__ __launch_bounds__(256) void scan_k(const int* __restrict__ counts,
                                              int* __restrict__ offs){
  __shared__ int part[256];
  const int CH = (NN + 255) / 256;
  int t = threadIdx.x;
  int s = 0;
  for (int j = 0; j < CH; ++j){ int idx = t*CH + j; if (idx < NN) s += counts[idx]; }
  part[t] = s;
  __syncthreads();
  if (t == 0){
    int run = 0;
    for (int i = 0; i < 256; ++i){ int v = part[i]; part[i] = run; run += v; }
    offs[NN] = run;
  }
  __syncthreads();
  int run = part[t];
  for (int j = 0; j < CH; ++j){
    int idx = t*CH + j;
    if (idx < NN){ offs[idx] = run; run += counts[idx]; }
  }
}

// ---- geometry + scatter into CSR (dst-sorted) order ----
__global__ __launch_bounds__(256) void geoscat_k(const int* __restrict__ edges,
                                                 const float* __restrict__ x,
                                                 const int* __restrict__ offs,
                                                 int* __restrict__ cursor,
                                                 int* __restrict__ edge_s,
                                                 float* __restrict__ dS,
                                                 float* __restrict__ dirsS,
                                                 float* __restrict__ rbfS){
  int e = blockIdx.x * 256 + threadIdx.x;
  if (e >= EN) return;
  int dst = edges[2*e], src = edges[2*e+1];
  float dx = x[dst*3+0] - x[src*3+0];
  float dy = x[dst*3+1] - x[src*3+1];
  float dz = x[dst*3+2] - x[src*3+2];
  float dd = sqrtf(dx*dx + dy*dy + dz*dz + 1e-10f);
  float inv = 1.f / (dd + 1e-5f);
  int pos = offs[dst] + atomicAdd(&cursor[dst], 1);
  edge_s[2*pos]   = dst;
  edge_s[2*pos+1] = src;
  dS[pos]   = dd;
  rbfS[pos] = __expf(-dd);
  dirsS[3*pos+0] = dx*inv; dirsS[3*pos+1] = dy*inv; dirsS[3*pos+2] = dz*inv;
}

// ---- h (fp32) -> hbf (bf16 cache) + node_in[:,0:64] (pre-loop only) ----
__global__ __launch_bounds__(256) void h2b_k(const float* __restrict__ h,
                                             u16* __restrict__ hbf,
                                             u16* __restrict__ node_in){
  int gid = blockIdx.x * 256 + threadIdx.x;
  if (gid >= NN*64) return;
  int n = gid >> 6, ch = gid & 63;
  u16 b = f2bf(h[gid]);
  hbf[gid] = b;
  node_in[(size_t)n*384 + ch] = b;
}

// ---- generic weight convert+transpose: dst[l][n][k] = bf16(src[l][k][n]) ----
__global__ void convw_k(const float* __restrict__ src, int K, int N, size_t sStride,
                        u16* __restrict__ dst, int Kpad, int Npad, size_t dStride){
  int idx = blockIdx.x * 256 + threadIdx.x;
  if (idx >= Npad*Kpad) return;
  int n = idx / Kpad, k = idx - n*Kpad;
  float v = (k < K && n < N) ? src[blockIdx.y*sStride + (size_t)k*N + n] : 0.f;
  dst[blockIdx.y*dStride + idx] = f2bf(v);
}

// ---- xmix reorganize: Xr[l][hd][n][q] = bf16(xmix[l][4q+hd][n]) ----
__global__ __launch_bounds__(256) void convx_k(const float* __restrict__ xmix,
                                               u16* __restrict__ xr){
  int idx = blockIdx.x * 256 + threadIdx.x;   // 0..65535
  int l = blockIdx.y;
  int q  = idx & 63;
  int n  = (idx >> 6) & 255;
  int hd = idx >> 14;
  xr[(size_t)l*65536 + idx] = f2bf(xmix[(size_t)l*65536 + (size_t)(4*q + hd)*256 + n]);
}

// ==== FUSED EDGE KERNEL: gather hc -> Win GEMM -> rbf -> W1 GEMM -> W2 GEMM -> sem ====
__global__ __launch_bounds__(256) void edge_fused_k(
    const int* __restrict__ edge_s,
    const u16* __restrict__ hbf,
    const float* __restrict__ rbfS,
    const float* __restrict__ dS,
    const u16* __restrict__ Winb,   // 64 x 128 (N x K)
    const float* __restrict__ bin,
    const float* __restrict__ mean,
    const float* __restrict__ beta,
    const u16* __restrict__ W1b,    // 64 x 192
    const float* __restrict__ b1,
    const u16* __restrict__ W2b,    // 64 x 64
    const float* __restrict__ b2,
    const float* __restrict__ sw,   // 64 x 4
    const float* __restrict__ sb,   // 4
    u16* __restrict__ he,
    float* __restrict__ logit){
  __shared__ u16 HC[64*132];
  __shared__ u16 T2[64*72];
  __shared__ u16 HE1[64*72];
  const int tid = threadIdx.x, lane = tid & 63, wv = tid >> 6;
  const int l15 = lane & 15, kq = (lane >> 4) * 8;
  const int rsub = (lane >> 4) << 2;
  const int e0 = blockIdx.x * 64;
  const int nw = wv*16 + l15;   // this lane's weight-row (output col)

  // P0: gather HC
#pragma unroll
  for (int i = 0; i < 4; ++i){
    int idx = tid + i*256;
    int row = idx >> 4, c = idx & 15;
    int e = min(e0 + row, EN - 1);
    int node = (c < 8) ? edge_s[2*e] : edge_s[2*e+1];
    *reinterpret_cast<uint4*>(HC + row*132 + c*8) =
        *reinterpret_cast<const uint4*>(hbf + (size_t)node*64 + (c & 7)*8);
  }
  __syncthreads();

  // P1: hm = hc @ Win ; epilogue rbf-scale -> T2
  f32x4 acc[4];
#pragma unroll
  for (int mt = 0; mt < 4; ++mt) acc[mt] = (f32x4){0.f,0.f,0.f,0.f};
#pragma unroll
  for (int kc = 0; kc < 128; kc += 32){
    bf16x8 bf = ldg_bf8(Winb + nw*128 + kc + kq);
#pragma unroll
    for (int mt = 0; mt < 4; ++mt){
      bf16x8 af = *reinterpret_cast<const bf16x8*>(HC + (mt*16 + l15)*132 + kc + kq);
      acc[mt] = __builtin_amdgcn_mfma_f32_16x16x32_bf16(af, bf, acc[mt], 0, 0, 0);
    }
  }
  {
    float bi = 0.f, mn = 0.f, bt = 0.f;
    if (nw < 50){ bi = bin[nw]; mn = mean[nw]; bt = beta[nw]; }
#pragma unroll
    for (int mt = 0; mt < 4; ++mt){
#pragma unroll
      for (int r = 0; r < 4; ++r){
        int row = mt*16 + rsub + r;
        int e = min(e0 + row, EN - 1);
        float v;
        if (nw < 50){ float df = rbfS[e] - mn; v = __expf(-bt*df*df) * (acc[mt][r] + bi); }
        else if (nw == 50) v = dS[e];
        else v = 0.f;
        T2[row*72 + nw] = f2bf(v);
      }
    }
  }
  __syncthreads();

  // P3: he1 = silu(hc@W1a + T2@W1b + b1)
#pragma unroll
  for (int mt = 0; mt < 4; ++mt) acc[mt] = (f32x4){0.f,0.f,0.f,0.f};
#pragma unroll
  for (int kc = 0; kc < 128; kc += 32){
    bf16x8 bf = ldg_bf8(W1b + nw*192 + kc + kq);
#pragma unroll
    for (int mt = 0; mt < 4; ++mt){
      bf16x8 af = *reinterpret_cast<const bf16x8*>(HC + (mt*16 + l15)*132 + kc + kq);
      acc[mt] = __builtin_amdgcn_mfma_f32_16x16x32_bf16(af, bf, acc[mt], 0, 0, 0);
    }
  }
#pragma unroll
  for (int kc = 128; kc < 192; kc += 32){
    bf16x8 bf = ldg_bf8(W1b + nw*192 + kc + kq);
#pragma unroll
    for (int mt = 0; mt < 4; ++mt){
      bf16x8 af = *reinterpret_cast<const bf16x8*>(T2 + (mt*16 + l15)*72 + (kc-128) + kq);
      acc[mt] = __builtin_amdgcn_mfma_f32_16x16x32_bf16(af, bf, acc[mt], 0, 0, 0);
    }
  }
  {
    float bb = b1[nw];
#pragma unroll
    for (int mt = 0; mt < 4; ++mt){
#pragma unroll
      for (int r = 0; r < 4; ++r){
        int row = mt*16 + rsub + r;
        HE1[row*72 + nw] = f2bf(siluf(acc[mt][r] + bb));
      }
    }
  }
  __syncthreads();

  // P5: he = he1 @ W2 + b2 -> global + T2 (for sem)
#pragma unroll
  for (int mt = 0; mt < 4; ++mt) acc[mt] = (f32x4){0.f,0.f,0.f,0.f};
#pragma unroll
  for (int kc = 0; kc < 64; kc += 32){
    bf16x8 bf = ldg_bf8(W2b + nw*64 + kc + kq);
#pragma unroll
    for (int mt = 0; mt < 4; ++mt){
      bf16x8 af = *reinterpret_cast<const bf16x8*>(HE1 + (mt*16 + l15)*72 + kc + kq);
      acc[mt] = __builtin_amdgcn_mfma_f32_16x16x32_bf16(af, bf, acc[mt], 0, 0, 0);
    }
  }
  {
    float bb = b2[nw];
#pragma unroll
    for (int mt = 0; mt < 4; ++mt){
#pragma unroll
      for (int r = 0; r < 4; ++r){
        int row = mt*16 + rsub + r;
        int e = e0 + row;
        u16 hb = f2bf(acc[mt][r] + bb);
        if (e < EN) he[(size_t)e*64 + nw] = hb;
        T2[row*72 + nw] = hb;
      }
    }
  }
  __syncthreads();

  // P6: sem logits + celu(alpha=2)
  {
    int er = tid >> 2, hd = tid & 3;
    float a = sb[hd];
#pragma unroll 8
    for (int k = 0; k < 64; ++k)
      a = fmaf(bf2f(T2[er*72 + k]), sw[k*4 + hd], a);
    float v = a > 0.f ? a : 2.f*(__expf(0.5f*a) - 1.f);
    int e = e0 + er;
    if (e < EN) logit[(size_t)e*4 + hd] = v;
  }
}

// ==== XMIX (barrier-free: per-wave private LDS B slices) ====
// Block: 64 edge rows x 256 cols; wave w owns cols [64w,64w+64).
// Per hd, each wave stages its own 64x64 B slice (global->LDS, own slice only)
// and proceeds on its own lgkmcnt — NO __syncthreads anywhere.
// coef_raw[m][n] = sum_hd (he[m,:]*att[m][hd]) @ X_hd [n]   (tanh applied in agg_k)
__global__ __launch_bounds__(256) void xmix_k(const u16* __restrict__ he,
                                              const float* __restrict__ att,
                                              const u16* __restrict__ Xr,
                                              u16* __restrict__ coef){
  __shared__ u16 B_s[4][64*72];
  const int tid = threadIdx.x, lane = tid & 63, wave = tid >> 6;
  const int l15 = lane & 15, kq = (lane >> 4) * 8;
  const int rsub = (lane >> 4) << 2;
  const int m0 = blockIdx.x * 64;
  const int n0 = wave * 64;

  // A raw fragments (bf16) + per-row att for 4 row-subtiles
  bf16x8 araw[4][2];
  float4 attA[4];
#pragma unroll
  for (int s = 0; s < 4; ++s){
    int m = min(m0 + s*16 + l15, EN - 1);
    attA[s] = *reinterpret_cast<const float4*>(att + (size_t)m*4);
#pragma unroll
    for (int k2 = 0; k2 < 2; ++k2)
      araw[s][k2] = *reinterpret_cast<const bf16x8*>(he + (size_t)m*64 + k2*32 + kq);
  }

  f32x4 acc[4][4];
#pragma unroll
  for (int s = 0; s < 4; ++s)
#pragma unroll
    for (int c = 0; c < 4; ++c) acc[s][c] = (f32x4){0.f,0.f,0.f,0.f};

  u16* Bw = &B_s[wave][0];

#pragma unroll
  for (int hd = 0; hd < 4; ++hd){
    // stage this wave's 64x64 B slice: lane covers row `lane` (128 B)
    {
      const u16* src = Xr + ((size_t)hd*256 + n0 + lane)*64;
      u16* dst = Bw + lane*72;
#pragma unroll
      for (int j = 0; j < 8; ++j)
        *reinterpret_cast<uint4*>(dst + j*8) = *reinterpret_cast<const uint4*>(src + j*8);
    }
    // scaled A fragments for this hd (unpack raw bf16, scale, repack)
    bf16x8 afs[4][2];
#pragma unroll
    for (int s = 0; s < 4; ++s){
      float a = (hd==0) ? attA[s].x : (hd==1) ? attA[s].y
              : (hd==2) ? attA[s].z : attA[s].w;
#pragma unroll
      for (int k2 = 0; k2 < 2; ++k2){
        const u16* rp = reinterpret_cast<const u16*>(&araw[s][k2]);
        u16 o[8];
#pragma unroll
        for (int j = 0; j < 8; ++j) o[j] = f2bf(bf2f(rp[j]) * a);
        afs[s][k2] = *reinterpret_cast<bf16x8*>(o);
      }
    }
    // MFMA burst over this wave's private slice (compiler inserts lgkmcnt)
#pragma unroll
    for (int k2 = 0; k2 < 2; ++k2){
#pragma unroll
      for (int c = 0; c < 4; ++c){
        bf16x8 bf = *reinterpret_cast<const bf16x8*>(Bw + (c*16 + l15)*72 + k2*32 + kq);
#pragma unroll
        for (int s = 0; s < 4; ++s)
          acc[s][c] = __builtin_amdgcn_mfma_f32_16x16x32_bf16(afs[s][k2], bf, acc[s][c], 0, 0, 0);
      }
    }
  }

  // epilogue: store RAW (tanh deferred to agg_k)
#pragma unroll
  for (int s = 0; s < 4; ++s){
    const int rbase = m0 + s*16 + rsub;
#pragma unroll
    for (int c = 0; c < 4; ++c){
      int n = n0 + c*16 + l15;
#pragma unroll
      for (int r = 0; r < 4; ++r){
        int m = rbase + r;
        if (m < EN) coef[(size_t)m*256 + n] = f2bf(acc[s][c][r]);
      }
    }
  }
}

// ==== FUSED NODE BLOCK: pn-MLP (cnorm->h_comb via LDS) + node-MLP + residual ====
__global__ __launch_bounds__(256) void nodeblock_k(
    const u16* __restrict__ cnorm,                   // NN x 256
    const u16* __restrict__ P1t, const float* __restrict__ pb1,  // 64 x 256
    const u16* __restrict__ P2t, const float* __restrict__ pb2,  // 64 x 64
    const u16* __restrict__ node_in,                 // NN x 384 (cols 0..320 valid)
    const u16* __restrict__ N1t, const float* __restrict__ nb1,  // 64 x 384
    const u16* __restrict__ N2t, const float* __restrict__ nb2,  // 64 x 64
    const float* __restrict__ hres,
    float* __restrict__ hout,
    u16* __restrict__ hbf,
    u16* __restrict__ node_io){
  __shared__ u16 A_s[128*LP];
  __shared__ u16 B_s[64*LP];
  __shared__ u16 T_s[128*72];
  __shared__ u16 W2_s[64*72];
  __shared__ u16 HCm[128*72];   // h_comb
  const int tid = threadIdx.x, lane = tid & 63, wave = tid >> 6;
  const int m0 = blockIdx.x * 128;
  const int l15 = lane & 15, kq = (lane >> 4)*8;
  const int rsub = (lane >> 4) << 2;
  const int srow = tid >> 1, skh = (tid & 1)*16;
  const int arow = min(m0 + srow, NN - 1);
  const u16* aptr1 = cnorm + (size_t)arow*256 + skh;
  const u16* aptr2 = node_in + (size_t)arow*384 + skh;
  const int brow = tid >> 2, bcol = (tid & 3)*8;

  // stage pn W2^T
#pragma unroll
  for (int i = 0; i < 2; ++i){
    int idx = tid + i*256;
    int row = idx >> 3, cc = (idx & 7)*8;
    *reinterpret_cast<uint4*>(W2_s + row*72 + cc) =
        *reinterpret_cast<const uint4*>(P2t + row*64 + cc);
  }

  f32x4 acc0[4], acc1[4];
#pragma unroll
  for (int c = 0; c < 4; ++c){ acc0[c] = (f32x4){0,0,0,0}; acc1[c] = (f32x4){0,0,0,0}; }

  // pn GEMM1: K=256
  for (int kc = 0; kc < 256; kc += 32){
    *reinterpret_cast<uint4*>(A_s + srow*LP + skh)     = *reinterpret_cast<const uint4*>(aptr1 + kc);
    *reinterpret_cast<uint4*>(A_s + srow*LP + skh + 8) = *reinterpret_cast<const uint4*>(aptr1 + kc + 8);
    *reinterpret_cast<uint4*>(B_s + brow*LP + bcol) =
        *reinterpret_cast<const uint4*>(P1t + (size_t)brow*256 + kc + bcol);
    __syncthreads();
    bf16x8 af0 = *reinterpret_cast<const bf16x8*>(A_s + (wave*16 + l15)*LP + kq);
    bf16x8 af1 = *reinterpret_cast<const bf16x8*>(A_s + (64 + wave*16 + l15)*LP + kq);
#pragma unroll
    for (int c = 0; c < 4; ++c){
      bf16x8 bf = *reinterpret_cast<const bf16x8*>(B_s + (c*16 + l15)*LP + kq);
      acc0[c] = __builtin_amdgcn_mfma_f32_16x16x32_bf16(af0, bf, acc0[c], 0, 0, 0);
      acc1[c] = __builtin_amdgcn_mfma_f32_16x16x32_bf16(af1, bf, acc1[c], 0, 0, 0);
    }
    __syncthreads();
  }
  // epi1 -> T_s
#pragma unroll
  for (int h = 0; h < 2; ++h){
#pragma unroll
    for (int c = 0; c < 4; ++c){
      int n = c*16 + l15;
      float bb = pb1[n];
#pragma unroll
      for (int r = 0; r < 4; ++r){
        int rowloc = h*64 + wave*16 + rsub + r;
        float a = (h == 0) ? acc0[c][r] : acc1[c][r];
        T_s[rowloc*72 + n] = f2bf(siluf(a + bb));
      }
    }
  }
  __syncthreads();
  // pn GEMM2: K=64 -> h_comb -> HCm
#pragma unroll
  for (int c = 0; c < 4; ++c){ acc0[c] = (f32x4){0,0,0,0}; acc1[c] = (f32x4){0,0,0,0}; }
#pragma unroll
  for (int kc = 0; kc < 64; kc += 32){
    bf16x8 af0 = *reinterpret_cast<const bf16x8*>(T_s + (wave*16 + l15)*72 + kc + kq);
    bf16x8 af1 = *reinterpret_cast<const bf16x8*>(T_s + (64 + wave*16 + l15)*72 + kc + kq);
#pragma unroll
    for (int c = 0; c < 4; ++c){
      bf16x8 bf = *reinterpret_cast<const bf16x8*>(W2_s + (c*16 + l15)*72 + kc + kq);
      acc0[c] = __builtin_amdgcn_mfma_f32_16x16x32_bf16(af0, bf, acc0[c], 0, 0, 0);
      acc1[c] = __builtin_amdgcn_mfma_f32_16x16x32_bf16(af1, bf, acc1[c], 0, 0, 0);
    }
  }
#pragma unroll
  for (int h = 0; h < 2; ++h){
#pragma unroll
    for (int c = 0; c < 4; ++c){
      int n = c*16 + l15;
      float bb = pb2[n];
#pragma unroll
      for (int r = 0; r < 4; ++r){
        int rowloc = h*64 + wave*16 + rsub + r;
        float a = (h == 0) ? acc0[c][r] : acc1[c][r];
        HCm[rowloc*72 + n] = f2bf(siluf(a + bb));
      }
    }
  }
  __syncthreads();

  // node GEMM1: K=384 — cols 0..319 from global node_in, 320..383 from HCm
#pragma unroll
  for (int c = 0; c < 4; ++c){ acc0[c] = (f32x4){0,0,0,0}; acc1[c] = (f32x4){0,0,0,0}; }
  for (int kc = 0; kc < 320; kc += 32){
    *reinterpret_cast<uint4*>(A_s + srow*LP + skh)     = *reinterpret_cast<const uint4*>(aptr2 + kc);
    *reinterpret_cast<uint4*>(A_s + srow*LP + skh + 8) = *reinterpret_cast<const uint4*>(aptr2 + kc + 8);
    *reinterpret_cast<uint4*>(B_s + brow*LP + bcol) =
        *reinterpret_cast<const uint4*>(N1t + (size_t)brow*384 + kc + bcol);
    __syncthreads();
    bf16x8 af0 = *reinterpret_cast<const bf16x8*>(A_s + (wave*16 + l15)*LP + kq);
    bf16x8 af1 = *reinterpret_cast<const bf16x8*>(A_s + (64 + wave*16 + l15)*LP + kq);
#pragma unroll
    for (int c = 0; c < 4; ++c){
      bf16x8 bf = *reinterpret_cast<const bf16x8*>(B_s + (c*16 + l15)*LP + kq);
      acc0[c] = __builtin_amdgcn_mfma_f32_16x16x32_bf16(af0, bf, acc0[c], 0, 0, 0);
      acc1[c] = __builtin_amdgcn_mfma_f32_16x16x32_bf16(af1, bf, acc1[c], 0, 0, 0);
    }
    __syncthreads();
  }
#pragma unroll
  for (int kc = 320; kc < 384; kc += 32){
    bf16x8 af0 = *reinterpret_cast<const bf16x8*>(HCm + (wave*16 + l15)*72 + (kc-320) + kq);
    bf16x8 af1 = *reinterpret_cast<const bf16x8*>(HCm + (64 + wave*16 + l15)*72 + (kc-320) + kq);
#pragma unroll
    for (int c = 0; c < 4; ++c){
      bf16x8 bf = ldg_bf8(N1t + (size_t)(c*16 + l15)*384 + kc + kq);
      acc0[c] = __builtin_amdgcn_mfma_f32_16x16x32_bf16(af0, bf, acc0[c], 0, 0, 0);
      acc1[c] = __builtin_amdgcn_mfma_f32_16x16x32_bf16(af1, bf, acc1[c], 0, 0, 0);
    }
  }
  // epi1 -> T_s + stage node W2^T
#pragma unroll
  for (int h = 0; h < 2; ++h){
#pragma unroll
    for (int c = 0; c < 4; ++c){
      int n = c*16 + l15;
      float bb = nb1[n];
#pragma unroll
      for (int r = 0; r < 4; ++r){
        int rowloc = h*64 + wave*16 + rsub + r;
        float a = (h == 0) ? acc0[c][r] : acc1[c][r];
        T_s[rowloc*72 + n] = f2bf(siluf(a + bb));
      }
    }
  }
#pragma unroll
  for (int i = 0; i < 2; ++i){
    int idx = tid + i*256;
    int row = idx >> 3, cc = (idx & 7)*8;
    *reinterpret_cast<uint4*>(W2_s + row*72 + cc) =
        *reinterpret_cast<const uint4*>(N2t + row*64 + cc);
  }
  __syncthreads();
  // node GEMM2: K=64
#pragma unroll
  for (int c = 0; c < 4; ++c){ acc0[c] = (f32x4){0,0,0,0}; acc1[c] = (f32x4){0,0,0,0}; }
#pragma unroll
  for (int kc = 0; kc < 64; kc += 32){
    bf16x8 af0 = *reinterpret_cast<const bf16x8*>(T_s + (wave*16 + l15)*72 + kc + kq);
    bf16x8 af1 = *reinterpret_cast<const bf16x8*>(T_s + (64 + wave*16 + l15)*72 + kc + kq);
#pragma unroll
    for (int c = 0; c < 4; ++c){
      bf16x8 bf = *reinterpret_cast<const bf16x8*>(W2_s + (c*16 + l15)*72 + kc + kq);
      acc0[c] = __builtin_amdgcn_mfma_f32_16x16x32_bf16(af0, bf, acc0[c], 0, 0, 0);
      acc1[c] = __builtin_amdgcn_mfma_f32_16x16x32_bf16(af1, bf, acc1[c], 0, 0, 0);
    }
  }
  // epi: h' = h + silu(.)
#pragma unroll
  for (int h = 0; h < 2; ++h){
#pragma unroll
    for (int c = 0; c < 4; ++c){
      int n = c*16 + l15;
      float bb = nb2[n];
#pragma unroll
      for (int r = 0; r < 4; ++r){
        int m = m0 + h*64 + wave*16 + rsub + r;
        if (m >= NN) continue;
        float a = (h == 0) ? acc0[c][r] : acc1[c][r];
        float hn = hres[(size_t)m*64 + n] + siluf(a + bb);
        hout[(size_t)m*64 + n] = hn;
        u16 bbf = f2bf(hn);
        hbf[(size_t)m*64 + n] = bbf;
        node_io[(size_t)m*384 + n] = bbf;
      }
    }
  }
}

// ==== 2-layer MLP (epilogue head): fp32 out = silu(A@W1+b1)@W2 + b2 ====
__global__ __launch_bounds__(256) void mlp2_head_k(const u16* __restrict__ A,
                                                   const u16* __restrict__ W1t,
                                                   const float* __restrict__ b1,
                                                   const u16* __restrict__ W2t,
                                                   const float* __restrict__ b2,
                                                   float* __restrict__ outf){
  __shared__ u16 A_s[128*LP];
  __shared__ u16 B_s[64*LP];
  __shared__ u16 T_s[128*72];
  __shared__ u16 W2_s[64*72];
  const int tid = threadIdx.x, lane = tid & 63, wave = tid >> 6;
  const int m0 = blockIdx.x * 128;
  const int l15 = lane & 15, kq = (lane >> 4)*8;
  const int rsub = (lane >> 4) << 2;
#pragma unroll
  for (int i = 0; i < 2; ++i){
    int idx = tid + i*256;
    int row = idx >> 3, cc = (idx & 7)*8;
    *reinterpret_cast<uint4*>(W2_s + row*72 + cc) =
        *reinterpret_cast<const uint4*>(W2t + row*64 + cc);
  }
  const int srow = tid >> 1, skh = (tid & 1)*16;
  const int arow = min(m0 + srow, NN - 1);
  const u16* aptr = A + (size_t)arow*64 + skh;

  f32x4 acc0[4], acc1[4];
#pragma unroll
  for (int c = 0; c < 4; ++c){ acc0[c] = (f32x4){0,0,0,0}; acc1[c] = (f32x4){0,0,0,0}; }
  const int brow = tid >> 2, bcol = (tid & 3)*8;
  for (int kc = 0; kc < 64; kc += 32){
    *reinterpret_cast<uint4*>(A_s + srow*LP + skh)     = *reinterpret_cast<const uint4*>(aptr + kc);
    *reinterpret_cast<uint4*>(A_s + srow*LP + skh + 8) = *reinterpret_cast<const uint4*>(aptr + kc + 8);
    *reinterpret_cast<uint4*>(B_s + brow*LP + bcol) =
        *reinterpret_cast<const uint4*>(W1t + (size_t)brow*64 + kc + bcol);
    __syncthreads();
    bf16x8 af0 = *reinterpret_cast<const bf16x8*>(A_s + (wave*16 + l15)*LP + kq);
    bf16x8 af1 = *reinterpret_cast<const bf16x8*>(A_s + (64 + wave*16 + l15)*LP + kq);
#pragma unroll
    for (int c = 0; c < 4; ++c){
      bf16x8 bf = *reinterpret_cast<const bf16x8*>(B_s + (c*16 + l15)*LP + kq);
      acc0[c] = __builtin_amdgcn_mfma_f32_16x16x32_bf16(af0, bf, acc0[c], 0, 0, 0);
      acc1[c] = __builtin_amdgcn_mfma_f32_16x16x32_bf16(af1, bf, acc1[c], 0, 0, 0);
    }
    __syncthreads();
  }
#pragma unroll
  for (int h = 0; h < 2; ++h){
#pragma unroll
    for (int c = 0; c < 4; ++c){
      int n = c*16 + l15;
      float bb = b1[n];
#pragma unroll
      for (int r = 0; r < 4; ++r){
        int rowloc = h*64 + wave*16 + rsub + r;
        float a = (h == 0) ? acc0[c][r] : acc1[c][r];
        T_s[rowloc*72 + n] = f2bf(siluf(a + bb));
      }
    }
  }
  __syncthreads();
#pragma unroll
  for (int c = 0; c < 4; ++c){ acc0[c] = (f32x4){0,0,0,0}; acc1[c] = (f32x4){0,0,0,0}; }
#pragma unroll
  for (int kc = 0; kc < 64; kc += 32){
    bf16x8 af0 = *reinterpret_cast<const bf16x8*>(T_s + (wave*16 + l15)*72 + kc + kq);
    bf16x8 af1 = *reinterpret_cast<const bf16x8*>(T_s + (64 + wave*16 + l15)*72 + kc + kq);
#pragma unroll
    for (int c = 0; c < 4; ++c){
      bf16x8 bf = *reinterpret_cast<const bf16x8*>(W2_s + (c*16 + l15)*72 + kc + kq);
      acc0[c] = __builtin_amdgcn_mfma_f32_16x16x32_bf16(af0, bf, acc0[c], 0, 0, 0);
      acc1[c] = __builtin_amdgcn_mfma_f32_16x16x32_bf16(af1, bf, acc1[c], 0, 0, 0);
    }
  }
#pragma unroll
  for (int h = 0; h < 2; ++h){
#pragma unroll
    for (int c = 0; c < 4; ++c){
      int n = c*16 + l15;
      float bb = b2[n];
#pragma unroll
      for (int r = 0; r < 4; ++r){
        int m = m0 + h*64 + wave*16 + rsub + r;
        if (m >= NN) continue;
        float a = (h == 0) ? acc0[c][r] : acc1[c][r];
        outf[(size_t)m*64 + n] = a + bb;
      }
    }
  }
}

// ---- generic tiled fp32 GEMM (small cases) ----
template<int EPI>
__global__ __launch_bounds__(256) void gemm_k(const float* __restrict__ A, int lda,
                                              const float* __restrict__ W, int ldw,
                                              const float* __restrict__ bias,
                                              float* __restrict__ out, int ldo, int ocol,
                                              int M, int N, int K){
  __shared__ float w_s[128*64];
  const int tid  = threadIdx.x;
  const int nl   = tid & 63;
  const int rg   = tid >> 6;
  const int col0 = blockIdx.y * 64;
  const int m0   = blockIdx.x * 16 + rg * 4;
  float acc[4] = {0.f, 0.f, 0.f, 0.f};
  const float* ar[4];
#pragma unroll
  for (int r = 0; r < 4; ++r){
    int mr = min(m0 + r, M - 1);
    ar[r] = A + (size_t)mr * lda;
  }
  for (int kc = 0; kc < K; kc += 128){
    int kn = min(128, K - kc);
    for (int idx = tid; idx < 128*64; idx += 256){
      int kk = idx >> 6, nn = idx & 63;
      int gn = col0 + nn;
      w_s[idx] = (kk < kn && gn < N) ? W[(size_t)(kc+kk)*ldw + gn] : 0.f;
    }
    __syncthreads();
    for (int k = 0; k < kn; ++k){
      float wv = w_s[k*64 + nl];
#pragma unroll
      for (int r = 0; r < 4; ++r) acc[r] = fmaf(ar[r][kc + k], wv, acc[r]);
    }
    __syncthreads();
  }
  int n = col0 + nl;
  if (n >= N) return;
  float b = bias ? bias[n] : 0.f;
#pragma unroll
  for (int r = 0; r < 4; ++r){
    int m = m0 + r;
    if (m >= M) break;
    float a = acc[r] + b;
    out[(size_t)m*ldo + ocol + n] = (EPI == 1) ? siluf(a) : a;
  }
}

// ---- per-node attention over contiguous CSR segment ----
__global__ __launch_bounds__(256) void att_k(const int* __restrict__ offs,
                                             const float* __restrict__ dS,
                                             const float* __restrict__ logit,
                                             float* __restrict__ att){
  int lane = threadIdx.x & 63;
  int node = (blockIdx.x * 256 + threadIdx.x) >> 6;
  if (node >= NN) return;
  int s0 = offs[node];
  int cnt = offs[node+1] - s0;
  if (cnt <= 0) return;
  const float NEG = -1e30f;
  if (cnt <= 64){
    bool act = lane < cnt;
    int p = s0 + (act ? lane : 0);
    float dd = dS[p];
    float4 lg = *reinterpret_cast<const float4*>(logit + 4*(size_t)p);
    float me  = wred_max(act ? -dd  : NEG);
    float ms0 = wred_max(act ? lg.x : NEG);
    float ms1 = wred_max(act ? lg.y : NEG);
    float ms2 = wred_max(act ? lg.z : NEG);
    float ms3 = wred_max(act ? lg.w : NEG);
    float ee  = act ? __expf(-dd - me)  : 0.f;
    float v0  = act ? __expf(lg.x - ms0) : 0.f;
    float v1  = act ? __expf(lg.y - ms1) : 0.f;
    float v2  = act ? __expf(lg.z - ms2) : 0.f;
    float v3  = act ? __expf(lg.w - ms3) : 0.f;
    float ise = 1.f / wred_sum(ee);
    float is0 = 1.f / wred_sum(v0);
    float is1 = 1.f / wred_sum(v1);
    float is2 = 1.f / wred_sum(v2);
    float is3 = 1.f / wred_sum(v3);
    float ae = ee * ise;
    float a0 = ae * v0 * is0, a1 = ae * v1 * is1;
    float a2 = ae * v2 * is2, a3 = ae * v3 * is3;
    float iz0 = 1.f / wred_sum(a0), iz1 = 1.f / wred_sum(a1);
    float iz2 = 1.f / wred_sum(a2), iz3 = 1.f / wred_sum(a3);
    if (act){
      float4 o; o.x = a0*iz0; o.y = a1*iz1; o.z = a2*iz2; o.w = a3*iz3;
      *reinterpret_cast<float4*>(att + 4*(size_t)p) = o;
    }
    return;
  }
  float me = NEG, ms0 = NEG, ms1 = NEG, ms2 = NEG, ms3 = NEG;
  for (int j = lane; j < cnt; j += 64){
    int p = s0 + j;
    float dd = dS[p];
    me = fmaxf(me, -dd);
    float4 lg = *reinterpret_cast<const float4*>(logit + 4*(size_t)p);
    ms0 = fmaxf(ms0, lg.x); ms1 = fmaxf(ms1, lg.y);
    ms2 = fmaxf(ms2, lg.z); ms3 = fmaxf(ms3, lg.w);
  }
  me = wred_max(me); ms0 = wred_max(ms0); ms1 = wred_max(ms1);
  ms2 = wred_max(ms2); ms3 = wred_max(ms3);
  float se = 0.f, ss0 = 0.f, ss1 = 0.f, ss2 = 0.f, ss3 = 0.f;
  for (int j = lane; j < cnt; j += 64){
    int p = s0 + j;
    float dd = dS[p];
    float4 lg = *reinterpret_cast<const float4*>(logit + 4*(size_t)p);
    se  += __expf(-dd - me);
    ss0 += __expf(lg.x - ms0); ss1 += __expf(lg.y - ms1);
    ss2 += __expf(lg.z - ms2); ss3 += __expf(lg.w - ms3);
  }
  se = wred_sum(se); ss0 = wred_sum(ss0); ss1 = wred_sum(ss1);
  ss2 = wred_sum(ss2); ss3 = wred_sum(ss3);
  float ise = 1.f/se, is0 = 1.f/ss0, is1 = 1.f/ss1, is2 = 1.f/ss2, is3 = 1.f/ss3;
  float z0 = 0.f, z1 = 0.f, z2 = 0.f, z3 = 0.f;
  for (int j = lane; j < cnt; j += 64){
    int p = s0 + j;
    float dd = dS[p];
    float4 lg = *reinterpret_cast<const float4*>(logit + 4*(size_t)p);
    float ae = __expf(-dd - me) * ise;
    z0 += ae * __expf(lg.x - ms0) * is0;
    z1 += ae * __expf(lg.y - ms1) * is1;
    z2 += ae * __expf(lg.z - ms2) * is2;
    z3 += ae * __expf(lg.w - ms3) * is3;
  }
  z0 = wred_sum(z0); z1 = wred_sum(z1); z2 = wred_sum(z2); z3 = wred_sum(z3);
  float iz0 = 1.f/z0, iz1 = 1.f/z1, iz2 = 1.f/z2, iz3 = 1.f/z3;
  for (int j = lane; j < cnt; j += 64){
    int p = s0 + j;
    float dd = dS[p];
    float4 lg = *reinterpret_cast<const float4*>(logit + 4*(size_t)p);
    float ae = __expf(-dd - me) * ise;
    float4 o;
    o.x = ae * __expf(lg.x - ms0) * is0 * iz0;
    o.y = ae * __expf(lg.y - ms1) * is1 * iz1;
    o.z = ae * __expf(lg.z - ms2) * is2 * iz2;
    o.w = ae * __expf(lg.w - ms3) * is3 * iz3;
    *reinterpret_cast<float4*>(att + 4*(size_t)p) = o;
  }
}

// ---- per-node aggregate (contiguous CSR), 2x unrolled; applies tanh to raw coef ----
__global__ __launch_bounds__(256) void agg_k(const int* __restrict__ offs,
                                             const u16* __restrict__ coef,
                                             const u16* __restrict__ he,
                                             const float* __restrict__ att,
                                             const float* __restrict__ dirsS,
                                             u16* __restrict__ cnorm,
                                             u16* __restrict__ node_in){
  int node = blockIdx.x;
  int c = threadIdx.x;
  int s0 = offs[node], s1 = offs[node+1];
  int q = c >> 2, hd = c & 3;
  float cs0 = 0.f, cs1 = 0.f, cs2 = 0.f, ha = 0.f;
  int p = s0;
  for (; p + 2 <= s1; p += 2){
    float co0 = fast_tanh(bf2f(coef[(size_t)p*256 + c]));
    float co1 = fast_tanh(bf2f(coef[(size_t)(p+1)*256 + c]));
    float hv0 = bf2f(he[(size_t)p*64 + q]);
    float hv1 = bf2f(he[(size_t)(p+1)*64 + q]);
    float av0 = att[(size_t)p*4 + hd];
    float av1 = att[(size_t)(p+1)*4 + hd];
    float d00 = dirsS[3*(size_t)p],     d01 = dirsS[3*(size_t)p+1],     d02 = dirsS[3*(size_t)p+2];
    float d10 = dirsS[3*(size_t)(p+1)], d11 = dirsS[3*(size_t)(p+1)+1], d12 = dirsS[3*(size_t)(p+1)+2];
    cs0 = fmaf(co0, d00, cs0); cs1 = fmaf(co0, d01, cs1); cs2 = fmaf(co0, d02, cs2);
    cs0 = fmaf(co1, d10, cs0); cs1 = fmaf(co1, d11, cs1); cs2 = fmaf(co1, d12, cs2);
    ha = fmaf(hv0, av0, ha);
    ha = fmaf(hv1, av1, ha);
  }
  if (p < s1){
    float co = fast_tanh(bf2f(coef[(size_t)p*256 + c]));
    float hv = bf2f(he[(size_t)p*64 + q]);
    float av = att[(size_t)p*4 + hd];
    float d0 = dirsS[3*(size_t)p], d1 = dirsS[3*(size_t)p+1], d2 = dirsS[3*(size_t)p+2];
    cs0 = fmaf(co, d0, cs0); cs1 = fmaf(co, d1, cs1); cs2 = fmaf(co, d2, cs2);
    ha = fmaf(hv, av, ha);
  }
  cnorm[(size_t)node*256 + c] = f2bf(cs0*cs0 + cs1*cs1 + cs2*cs2);
  node_in[(size_t)node*384 + 64 + c] = f2bf(ha);
}

// ---- graph pooling ----
__global__ __launch_bounds__(256) void segy_k(const float* __restrict__ hf,
                                              const int* __restrict__ seg,
                                              float* __restrict__ y){
  int gid = blockIdx.x * 256 + threadIdx.x;
  if (gid >= NN*64) return;
  int n = gid >> 6, ch = gid & 63;
  atomicAdd(&y[seg[n]*64 + ch], hf[gid]);
}

// ---- final head ----
__global__ void headf_k(const float* __restrict__ t2,
                        const float* __restrict__ w2,
                        const float* __restrict__ b2,
                        float* __restrict__ out){
  int s = threadIdx.x;
  if (s >= NSEG) return;
  float acc = b2[0];
  for (int k = 0; k < 64; ++k) acc = fmaf(t2[s*64 + k], w2[k], acc);
  out[s] = acc;
}

extern "C" void kernel_launch(void* const* d_in, const int* in_sizes, int n_in,
                              void* d_out, int out_size, void* d_ws, size_t ws_size,
                              hipStream_t stream) {
  (void)in_sizes; (void)n_in; (void)out_size; (void)ws_size;
  const float* in_i       = (const float*)d_in[0];
  const float* in_x       = (const float*)d_in[1];
  const float* emb_in_w   = (const float*)d_in[2];
  const float* emb_in_b   = (const float*)d_in[3];
  const float* edge_in_w  = (const float*)d_in[4];
  const float* edge_in_b  = (const float*)d_in[5];
  const float* rbf_means  = (const float*)d_in[6];
  const float* rbf_betas  = (const float*)d_in[7];
  const float* edge_o_w1  = (const float*)d_in[8];
  const float* edge_o_b1  = (const float*)d_in[9];
  const float* edge_o_w2  = (const float*)d_in[10];
  const float* edge_o_b2  = (const float*)d_in[11];
  const float* sem_w      = (const float*)d_in[12];
  const float* sem_b      = (const float*)d_in[13];
  const float* xmix_w     = (const float*)d_in[14];
  const float* pn_w1      = (const float*)d_in[15];
  const float* pn_b1      = (const float*)d_in[16];
  const float* pn_w2      = (const float*)d_in[17];
  const float* pn_b2      = (const float*)d_in[18];
  const float* node_w1    = (const float*)d_in[19];
  const float* node_b1    = (const float*)d_in[20];
  const float* node_w2    = (const float*)d_in[21];
  const float* node_b2    = (const float*)d_in[22];
  const float* emb_o_w1   = (const float*)d_in[23];
  const float* emb_o_b1   = (const float*)d_in[24];
  const float* emb_o_w2   = (const float*)d_in[25];
  const float* emb_o_b2   = (const float*)d_in[26];
  const float* head_w1    = (const float*)d_in[27];
  const float* head_b1    = (const float*)d_in[28];
  const float* head_w2    = (const float*)d_in[29];
  const float* head_b2    = (const float*)d_in[30];
  const int*   edges      = (const int*)d_in[31];
  const int*   segs       = (const int*)d_in[32];
  float* out = (float*)d_out;

  // workspace carve-up (256B aligned)
  char* base = (char*)d_ws;
  size_t off = 0;
  auto alloc = [&](size_t bytes) -> void* {
    void* p = base + off;
    off += (bytes + 255) & ~(size_t)255;
    return p;
  };
  float* dS     = (float*)alloc((size_t)EN*4);
  float* dirsS  = (float*)alloc((size_t)EN*3*4);
  float* rbfS   = (float*)alloc((size_t)EN*4);
  int*   edge_s = (int*)alloc((size_t)EN*2*4);
  float* hA     = (float*)alloc((size_t)NN*64*4);
  float* hB     = (float*)alloc((size_t)NN*64*4);
  u16*   he     = (u16*)alloc((size_t)EN*64*2);
  u16*   coef   = (u16*)alloc((size_t)EN*256*2);
  float* logit  = (float*)alloc((size_t)EN*4*4);
  float* att    = (float*)alloc((size_t)EN*4*4);
  u16*   hbf    = (u16*)alloc((size_t)NN*64*2);
  u16*   node_in= (u16*)alloc((size_t)NN*384*2);
  u16*   cnorm  = (u16*)alloc((size_t)NN*256*2);
  float* y      = (float*)alloc((size_t)NSEG*64*4);
  float* t2     = (float*)alloc((size_t)NSEG*64*4);
  u16* winb  = (u16*)alloc((size_t)DEPTH*64*128*2);
  u16* w1b   = (u16*)alloc((size_t)DEPTH*64*192*2);
  u16* w2b   = (u16*)alloc((size_t)DEPTH*64*64*2);
  u16* xr    = (u16*)alloc((size_t)DEPTH*4*256*64*2);   // [l][hd][n][q]
  u16* pw1b  = (u16*)alloc((size_t)DEPTH*64*256*2);
  u16* pw2b  = (u16*)alloc((size_t)DEPTH*64*64*2);
  u16* nw1b  = (u16*)alloc((size_t)DEPTH*64*384*2);
  u16* nw2b  = (u16*)alloc((size_t)DEPTH*64*64*2);
  u16* eo1b  = (u16*)alloc((size_t)64*64*2);
  u16* eo2b  = (u16*)alloc((size_t)64*64*2);
  int* counts   = (int*)alloc((size_t)NN*4);
  int* cursor   = (int*)alloc((size_t)NN*4);
  int* offs     = (int*)alloc((size_t)(NN+1)*4);

  hipMemsetAsync(counts, 0, (size_t)NN*4, stream);
  hipMemsetAsync(cursor, 0, (size_t)NN*4, stream);
  hipMemsetAsync(y, 0, (size_t)NSEG*64*4, stream);

  count_k<<<(EN+255)/256, 256, 0, stream>>>(edges, counts);
  scan_k<<<1, 256, 0, stream>>>(counts, offs);
  geoscat_k<<<(EN+255)/256, 256, 0, stream>>>(edges, in_x, offs, cursor,
                                              edge_s, dS, dirsS, rbfS);

  // weight conversions (once per call)
  convw_k<<<dim3(32,  DEPTH), 256, 0, stream>>>(edge_in_w, 128, 50, (size_t)128*50, winb, 128, 64, (size_t)64*128);
  convw_k<<<dim3(48,  DEPTH), 256, 0, stream>>>(edge_o_w1, 179, 64, (size_t)179*64, w1b,  192, 64, (size_t)64*192);
  convw_k<<<dim3(16,  DEPTH), 256, 0, stream>>>(edge_o_w2,  64, 64, (size_t)64*64,  w2b,   64, 64, (size_t)64*64);
  convx_k<<<dim3(256, DEPTH), 256, 0, stream>>>(xmix_w, xr);
  convw_k<<<dim3(64,  DEPTH), 256, 0, stream>>>(pn_w1,     256, 64, (size_t)256*64, pw1b, 256, 64, (size_t)64*256);
  convw_k<<<dim3(16,  DEPTH), 256, 0, stream>>>(pn_w2,      64, 64, (size_t)64*64,  pw2b,  64, 64, (size_t)64*64);
  convw_k<<<dim3(96,  DEPTH), 256, 0, stream>>>(node_w1,   384, 64, (size_t)384*64, nw1b, 384, 64, (size_t)64*384);
  convw_k<<<dim3(16,  DEPTH), 256, 0, stream>>>(node_w2,    64, 64, (size_t)64*64,  nw2b,  64, 64, (size_t)64*64);
  convw_k<<<dim3(16,  1),     256, 0, stream>>>(emb_o_w1,   64, 64, (size_t)64*64,  eo1b,  64, 64, (size_t)64*64);
  convw_k<<<dim3(16,  1),     256, 0, stream>>>(emb_o_w2,   64, 64, (size_t)64*64,  eo2b,  64, 64, (size_t)64*64);

  // h = i @ emb_in_w + b   (fp32, K=16)
  gemm_k<0><<<dim3((NN+15)/16, 1), 256, 0, stream>>>(
      in_i, 16, emb_in_w, 64, emb_in_b, hA, 64, 0, NN, 64, 16);
  h2b_k<<<(NN*64)/256, 256, 0, stream>>>(hA, hbf, node_in);

  const int EB  = (EN + 63) / 64;     // 1563 edge tiles
  const int NB2 = (NN + 127) / 128;   // 79

  float* hcur = hA;
  float* hnext = hB;
  for (int l = 0; l < DEPTH; ++l){
    const float* bin  = edge_in_b + (size_t)l*50;
    const float* mean = rbf_means + (size_t)l*50;
    const float* beta = rbf_betas + (size_t)l*50;
    const float* b1   = edge_o_b1 + (size_t)l*64;
    const float* b2   = edge_o_b2 + (size_t)l*64;
    const float* sw   = sem_w + (size_t)l*64*4;
    const float* sb   = sem_b + (size_t)l*4;
    const float* pb1  = pn_b1 + (size_t)l*64;
    const float* pb2  = pn_b2 + (size_t)l*64;
    const float* nb1  = node_b1 + (size_t)l*64;
    const float* nb2  = node_b2 + (size_t)l*64;
    const u16* Winb = winb + (size_t)l*64*128;
    const u16* W1b  = w1b  + (size_t)l*64*192;
    const u16* W2b  = w2b  + (size_t)l*64*64;
    const u16* Xrl  = xr   + (size_t)l*65536;
    const u16* P1b  = pw1b + (size_t)l*64*256;
    const u16* P2b  = pw2b + (size_t)l*64*64;
    const u16* N1b  = nw1b + (size_t)l*64*384;
    const u16* N2b  = nw2b + (size_t)l*64*64;

    edge_fused_k<<<EB, 256, 0, stream>>>(edge_s, hbf, rbfS, dS,
                                         Winb, bin, mean, beta,
                                         W1b, b1, W2b, b2, sw, sb,
                                         he, logit);
    att_k<<<(NN+3)/4, 256, 0, stream>>>(offs, dS, logit, att);
    xmix_k<<<EB, 256, 0, stream>>>(he, att, Xrl, coef);
    agg_k<<<NN, 256, 0, stream>>>(offs, coef, he, att, dirsS, cnorm, node_in);
    nodeblock_k<<<NB2, 256, 0, stream>>>(cnorm, P1b, pb1, P2b, pb2,
                                         node_in, N1b, nb1, N2b, nb2,
                                         hcur, hnext, hbf, node_in);
    float* tmp = hcur; hcur = hnext; hnext = tmp;
  }

  // output head: hnext = silu(hbf@eo1+b1)@eo2+b2  (bf16 MFMA, fp32 out)
  mlp2_head_k<<<NB2, 256, 0, stream>>>(hbf, eo1b, emb_o_b1, eo2b, emb_o_b2, hnext);
  segy_k<<<(NN*64)/256, 256, 0, stream>>>(hnext, segs, y);
  gemm_k<1><<<dim3((NSEG+15)/16, 1), 256, 0, stream>>>(
      y, 64, head_w1, 64, head_b1, t2, 64, 0, NSEG, 64, 64);
  headf_k<<<1, 128, 0, stream>>>(t2, head_w2, head_b2, out);
}

// Round 14
// 921.452 us; speedup vs baseline: 1.1000x; 1.1000x over previous
//
#include <hip/hip_runtime.h>
#include <hip/hip_bf16.h>

// ---- problem constants ----
constexpr int EN   = 100000;  // edges
constexpr int NN   = 10000;   // nodes
constexpr int DEPTH = 6;
constexpr int NSEG = 100;
constexpr int LP   = 40;      // padded LDS row stride (u16)

typedef unsigned short u16;
typedef __bf16 bf16x8 __attribute__((ext_vector_type(8)));
typedef float  f32x4  __attribute__((ext_vector_type(4)));

__device__ inline float wred_max(float v){
#pragma unroll
  for (int o = 32; o > 0; o >>= 1) v = fmaxf(v, __shfl_xor(v, o, 64));
  return v;
}
__device__ inline float wred_sum(float v){
#pragma unroll
  for (int o = 32; o > 0; o >>= 1) v += __shfl_xor(v, o, 64);
  return v;
}
__device__ inline float siluf(float x){ return x / (1.f + __expf(-x)); }
__device__ inline float fast_tanh(float x){
  float e = __expf(2.f * x);
  return 1.f - 2.f / (e + 1.f);
}
// fast RNE float->bf16 (finite inputs only; bitwise identical to RNE).
__device__ inline u16 f2bf(float x){
  unsigned u = __float_as_uint(x);
  u = u + 0x7FFFu + ((u >> 16) & 1u);
  return (u16)(u >> 16);
}
__device__ inline float bf2f(u16 u){
  union { float f; unsigned int ui; } v; v.ui = ((unsigned int)u) << 16; return v.f;
}
__device__ inline bf16x8 ldg_bf8(const u16* p){
  return *reinterpret_cast<const bf16x8*>(p);
}

// ---- dst histogram ----
__global__ __launch_bounds__(256) void count_k(const int* __restrict__ edges,
                                               int* __restrict__ counts){
  int e = blockIdx.x * 256 + threadIdx.x;
  if (e >= EN) return;
  atomicAdd(&counts[edges[2*e]], 1);
}

// ---- exclusive scan of counts -> offsets (single block) ----
__global__ __launch_bounds__(256) void scan_k(const int* __restrict__ counts,
                                              int* __restrict__ offs){
  __shared__ int part[256];
  const int CH = (NN + 255) / 256;
  int t = threadIdx.x;
  int s = 0;
  for (int j = 0; j < CH; ++j){ int idx = t*CH + j; if (idx < NN) s += counts[idx]; }
  part[t] = s;
  __syncthreads();
  if (t == 0){
    int run = 0;
    for (int i = 0; i < 256; ++i){ int v = part[i]; part[i] = run; run += v; }
    offs[NN] = run;
  }
  __syncthreads();
  int run = part[t];
  for (int j = 0; j < CH; ++j){
    int idx = t*CH + j;
    if (idx < NN){ offs[idx] = run; run += counts[idx]; }
  }
}

// ---- geometry + scatter into CSR (dst-sorted) order ----
__global__ __launch_bounds__(256) void geoscat_k(const int* __restrict__ edges,
                                                 const float* __restrict__ x,
                                                 const int* __restrict__ offs,
                                                 int* __restrict__ cursor,
                                                 int* __restrict__ edge_s,
                                                 float* __restrict__ dS,
                                                 float* __restrict__ dirsS,
                                                 float* __restrict__ rbfS){
  int e = blockIdx.x * 256 + threadIdx.x;
  if (e >= EN) return;
  int dst = edges[2*e], src = edges[2*e+1];
  float dx = x[dst*3+0] - x[src*3+0];
  float dy = x[dst*3+1] - x[src*3+1];
  float dz = x[dst*3+2] - x[src*3+2];
  float dd = sqrtf(dx*dx + dy*dy + dz*dz + 1e-10f);
  float inv = 1.f / (dd + 1e-5f);
  int pos = offs[dst] + atomicAdd(&cursor[dst], 1);
  edge_s[2*pos]   = dst;
  edge_s[2*pos+1] = src;
  dS[pos]   = dd;
  rbfS[pos] = __expf(-dd);
  dirsS[3*pos+0] = dx*inv; dirsS[3*pos+1] = dy*inv; dirsS[3*pos+2] = dz*inv;
}

// ---- h (fp32) -> hbf (bf16 cache) + node_in[:,0:64] (pre-loop only) ----
__global__ __launch_bounds__(256) void h2b_k(const float* __restrict__ h,
                                             u16* __restrict__ hbf,
                                             u16* __restrict__ node_in){
  int gid = blockIdx.x * 256 + threadIdx.x;
  if (gid >= NN*64) return;
  int n = gid >> 6, ch = gid & 63;
  u16 b = f2bf(h[gid]);
  hbf[gid] = b;
  node_in[(size_t)n*384 + ch] = b;
}

// ---- generic weight convert+transpose: dst[l][n][k] = bf16(src[l][k][n]) ----
__global__ void convw_k(const float* __restrict__ src, int K, int N, size_t sStride,
                        u16* __restrict__ dst, int Kpad, int Npad, size_t dStride){
  int idx = blockIdx.x * 256 + threadIdx.x;
  if (idx >= Npad*Kpad) return;
  int n = idx / Kpad, k = idx - n*Kpad;
  float v = (k < K && n < N) ? src[blockIdx.y*sStride + (size_t)k*N + n] : 0.f;
  dst[blockIdx.y*dStride + idx] = f2bf(v);
}

// ---- xmix reorganize: Xr[l][hd][n][q] = bf16(xmix[l][4q+hd][n]) ----
__global__ __launch_bounds__(256) void convx_k(const float* __restrict__ xmix,
                                               u16* __restrict__ xr){
  int idx = blockIdx.x * 256 + threadIdx.x;   // 0..65535
  int l = blockIdx.y;
  int q  = idx & 63;
  int n  = (idx >> 6) & 255;
  int hd = idx >> 14;
  xr[(size_t)l*65536 + idx] = f2bf(xmix[(size_t)l*65536 + (size_t)(4*q + hd)*256 + n]);
}

// ==== FUSED EDGE KERNEL: gather hc -> Win GEMM -> rbf -> W1 GEMM -> W2 GEMM -> sem ====
__global__ __launch_bounds__(256) void edge_fused_k(
    const int* __restrict__ edge_s,
    const u16* __restrict__ hbf,
    const float* __restrict__ rbfS,
    const float* __restrict__ dS,
    const u16* __restrict__ Winb,   // 64 x 128 (N x K)
    const float* __restrict__ bin,
    const float* __restrict__ mean,
    const float* __restrict__ beta,
    const u16* __restrict__ W1b,    // 64 x 192
    const float* __restrict__ b1,
    const u16* __restrict__ W2b,    // 64 x 64
    const float* __restrict__ b2,
    const float* __restrict__ sw,   // 64 x 4
    const float* __restrict__ sb,   // 4
    u16* __restrict__ he,
    float* __restrict__ logit){
  __shared__ u16 HC[64*132];
  __shared__ u16 T2[64*72];
  __shared__ u16 HE1[64*72];
  const int tid = threadIdx.x, lane = tid & 63, wv = tid >> 6;
  const int l15 = lane & 15, kq = (lane >> 4) * 8;
  const int rsub = (lane >> 4) << 2;
  const int e0 = blockIdx.x * 64;
  const int nw = wv*16 + l15;   // this lane's weight-row (output col)

  // P0: gather HC
#pragma unroll
  for (int i = 0; i < 4; ++i){
    int idx = tid + i*256;
    int row = idx >> 4, c = idx & 15;
    int e = min(e0 + row, EN - 1);
    int node = (c < 8) ? edge_s[2*e] : edge_s[2*e+1];
    *reinterpret_cast<uint4*>(HC + row*132 + c*8) =
        *reinterpret_cast<const uint4*>(hbf + (size_t)node*64 + (c & 7)*8);
  }
  __syncthreads();

  // P1: hm = hc @ Win ; epilogue rbf-scale -> T2
  f32x4 acc[4];
#pragma unroll
  for (int mt = 0; mt < 4; ++mt) acc[mt] = (f32x4){0.f,0.f,0.f,0.f};
#pragma unroll
  for (int kc = 0; kc < 128; kc += 32){
    bf16x8 bf = ldg_bf8(Winb + nw*128 + kc + kq);
#pragma unroll
    for (int mt = 0; mt < 4; ++mt){
      bf16x8 af = *reinterpret_cast<const bf16x8*>(HC + (mt*16 + l15)*132 + kc + kq);
      acc[mt] = __builtin_amdgcn_mfma_f32_16x16x32_bf16(af, bf, acc[mt], 0, 0, 0);
    }
  }
  {
    float bi = 0.f, mn = 0.f, bt = 0.f;
    if (nw < 50){ bi = bin[nw]; mn = mean[nw]; bt = beta[nw]; }
#pragma unroll
    for (int mt = 0; mt < 4; ++mt){
#pragma unroll
      for (int r = 0; r < 4; ++r){
        int row = mt*16 + rsub + r;
        int e = min(e0 + row, EN - 1);
        float v;
        if (nw < 50){ float df = rbfS[e] - mn; v = __expf(-bt*df*df) * (acc[mt][r] + bi); }
        else if (nw == 50) v = dS[e];
        else v = 0.f;
        T2[row*72 + nw] = f2bf(v);
      }
    }
  }
  __syncthreads();

  // P3: he1 = silu(hc@W1a + T2@W1b + b1)
#pragma unroll
  for (int mt = 0; mt < 4; ++mt) acc[mt] = (f32x4){0.f,0.f,0.f,0.f};
#pragma unroll
  for (int kc = 0; kc < 128; kc += 32){
    bf16x8 bf = ldg_bf8(W1b + nw*192 + kc + kq);
#pragma unroll
    for (int mt = 0; mt < 4; ++mt){
      bf16x8 af = *reinterpret_cast<const bf16x8*>(HC + (mt*16 + l15)*132 + kc + kq);
      acc[mt] = __builtin_amdgcn_mfma_f32_16x16x32_bf16(af, bf, acc[mt], 0, 0, 0);
    }
  }
#pragma unroll
  for (int kc = 128; kc < 192; kc += 32){
    bf16x8 bf = ldg_bf8(W1b + nw*192 + kc + kq);
#pragma unroll
    for (int mt = 0; mt < 4; ++mt){
      bf16x8 af = *reinterpret_cast<const bf16x8*>(T2 + (mt*16 + l15)*72 + (kc-128) + kq);
      acc[mt] = __builtin_amdgcn_mfma_f32_16x16x32_bf16(af, bf, acc[mt], 0, 0, 0);
    }
  }
  {
    float bb = b1[nw];
#pragma unroll
    for (int mt = 0; mt < 4; ++mt){
#pragma unroll
      for (int r = 0; r < 4; ++r){
        int row = mt*16 + rsub + r;
        HE1[row*72 + nw] = f2bf(siluf(acc[mt][r] + bb));
      }
    }
  }
  __syncthreads();

  // P5: he = he1 @ W2 + b2 -> global + T2 (for sem)
#pragma unroll
  for (int mt = 0; mt < 4; ++mt) acc[mt] = (f32x4){0.f,0.f,0.f,0.f};
#pragma unroll
  for (int kc = 0; kc < 64; kc += 32){
    bf16x8 bf = ldg_bf8(W2b + nw*64 + kc + kq);
#pragma unroll
    for (int mt = 0; mt < 4; ++mt){
      bf16x8 af = *reinterpret_cast<const bf16x8*>(HE1 + (mt*16 + l15)*72 + kc + kq);
      acc[mt] = __builtin_amdgcn_mfma_f32_16x16x32_bf16(af, bf, acc[mt], 0, 0, 0);
    }
  }
  {
    float bb = b2[nw];
#pragma unroll
    for (int mt = 0; mt < 4; ++mt){
#pragma unroll
      for (int r = 0; r < 4; ++r){
        int row = mt*16 + rsub + r;
        int e = e0 + row;
        u16 hb = f2bf(acc[mt][r] + bb);
        if (e < EN) he[(size_t)e*64 + nw] = hb;
        T2[row*72 + nw] = hb;
      }
    }
  }
  __syncthreads();

  // P6: sem logits + celu(alpha=2)
  {
    int er = tid >> 2, hd = tid & 3;
    float a = sb[hd];
#pragma unroll 8
    for (int k = 0; k < 64; ++k)
      a = fmaf(bf2f(T2[er*72 + k]), sw[k*4 + hd], a);
    float v = a > 0.f ? a : 2.f*(__expf(0.5f*a) - 1.f);
    int e = e0 + er;
    if (e < EN) logit[(size_t)e*4 + hd] = v;
  }
}

// ==== XMIX (hd-decomposed, double-buffered LDS B, att-scaled A) ====
// One block covers 128 rows x ALL 256 cols (two 128-col halves).
// coef_raw[m][n] = sum_hd (he[m,:]*att[m][hd]) @ X_hd [n]   (tanh applied in agg_k)
__global__ __launch_bounds__(256) void xmix_k(const u16* __restrict__ he,
                                              const float* __restrict__ att,
                                              const u16* __restrict__ Xr,
                                              u16* __restrict__ coef){
  __shared__ u16 B_s[2][128*72];
  const int tid = threadIdx.x, lane = tid & 63, wave = tid >> 6;
  const int l15 = lane & 15, kq = (lane >> 4) * 8;
  const int rsub = (lane >> 4) << 2;
  const int m0 = blockIdx.x * 128;

  const int srow = tid >> 1;
  const int scol = (tid & 1) * 32;

  // unpacked A row fragments (f32) + per-row att — loaded ONCE for both halves
  float a32[2][2][8];
  float4 attA[2];
#pragma unroll
  for (int h = 0; h < 2; ++h){
    int m = min(m0 + h*64 + wave*16 + l15, EN - 1);
    attA[h] = *reinterpret_cast<const float4*>(att + (size_t)m*4);
#pragma unroll
    for (int k2 = 0; k2 < 2; ++k2){
      ushort4 u0 = *reinterpret_cast<const ushort4*>(he + (size_t)m*64 + k2*32 + kq);
      ushort4 u1 = *reinterpret_cast<const ushort4*>(he + (size_t)m*64 + k2*32 + kq + 4);
      a32[h][k2][0] = bf2f(u0.x); a32[h][k2][1] = bf2f(u0.y);
      a32[h][k2][2] = bf2f(u0.z); a32[h][k2][3] = bf2f(u0.w);
      a32[h][k2][4] = bf2f(u1.x); a32[h][k2][5] = bf2f(u1.y);
      a32[h][k2][6] = bf2f(u1.z); a32[h][k2][7] = bf2f(u1.w);
    }
  }

  for (int nh = 0; nh < 2; ++nh){
    const int n0 = nh * 128;
    const u16* xsrc = Xr + ((size_t)(n0 + srow))*64 + scol;   // + hd*256*64

    // prefetch hd=0 B tile into registers
    uint4 pf0 = *reinterpret_cast<const uint4*>(xsrc);
    uint4 pf1 = *reinterpret_cast<const uint4*>(xsrc + 8);
    uint4 pf2 = *reinterpret_cast<const uint4*>(xsrc + 16);
    uint4 pf3 = *reinterpret_cast<const uint4*>(xsrc + 24);

    f32x4 acc[2][8];
#pragma unroll
    for (int h = 0; h < 2; ++h)
#pragma unroll
      for (int c = 0; c < 8; ++c) acc[h][c] = (f32x4){0.f,0.f,0.f,0.f};

    __syncthreads();   // previous half's reads of B_s complete (no-op cost on nh=0)
    {
      u16* dst = &B_s[0][srow*72 + scol];
      *reinterpret_cast<uint4*>(dst)      = pf0;
      *reinterpret_cast<uint4*>(dst + 8)  = pf1;
      *reinterpret_cast<uint4*>(dst + 16) = pf2;
      *reinterpret_cast<uint4*>(dst + 24) = pf3;
    }
    __syncthreads();

#pragma unroll
    for (int hd = 0; hd < 4; ++hd){
      if (hd < 3){
        const u16* s = xsrc + (size_t)(hd + 1) * 256 * 64;
        pf0 = *reinterpret_cast<const uint4*>(s);
        pf1 = *reinterpret_cast<const uint4*>(s + 8);
        pf2 = *reinterpret_cast<const uint4*>(s + 16);
        pf3 = *reinterpret_cast<const uint4*>(s + 24);
      }
      // scaled A fragments for this hd
      bf16x8 afs[2][2];
#pragma unroll
      for (int h = 0; h < 2; ++h){
        float a = (hd==0) ? attA[h].x : (hd==1) ? attA[h].y
                : (hd==2) ? attA[h].z : attA[h].w;
#pragma unroll
        for (int k2 = 0; k2 < 2; ++k2){
          u16 o[8];
#pragma unroll
          for (int j = 0; j < 8; ++j) o[j] = f2bf(a32[h][k2][j] * a);
          afs[h][k2] = *reinterpret_cast<bf16x8*>(o);
        }
      }
      const u16* Bb = &B_s[hd & 1][0];
#pragma unroll
      for (int k2 = 0; k2 < 2; ++k2){
#pragma unroll
        for (int c = 0; c < 8; ++c){
          bf16x8 bf = *reinterpret_cast<const bf16x8*>(Bb + (c*16 + l15)*72 + k2*32 + kq);
          acc[0][c] = __builtin_amdgcn_mfma_f32_16x16x32_bf16(afs[0][k2], bf, acc[0][c], 0, 0, 0);
          acc[1][c] = __builtin_amdgcn_mfma_f32_16x16x32_bf16(afs[1][k2], bf, acc[1][c], 0, 0, 0);
        }
      }
      if (hd < 3){
        u16* dst = &B_s[(hd + 1) & 1][srow*72 + scol];
        *reinterpret_cast<uint4*>(dst)      = pf0;
        *reinterpret_cast<uint4*>(dst + 8)  = pf1;
        *reinterpret_cast<uint4*>(dst + 16) = pf2;
        *reinterpret_cast<uint4*>(dst + 24) = pf3;
        __syncthreads();
      }
    }

    // epilogue: store RAW (tanh deferred to agg_k)
#pragma unroll
    for (int h = 0; h < 2; ++h){
      const int rbase = m0 + h*64 + wave*16 + rsub;
#pragma unroll
      for (int c = 0; c < 8; ++c){
        int n = n0 + c*16 + l15;
#pragma unroll
        for (int r = 0; r < 4; ++r){
          int m = rbase + r;
          if (m < EN) coef[(size_t)m*256 + n] = f2bf(acc[h][c][r]);
        }
      }
    }
  }
}

// ==== FUSED NODE BLOCK: pn-MLP (cnorm->h_comb via LDS) + node-MLP + residual ====
__global__ __launch_bounds__(256) void nodeblock_k(
    const u16* __restrict__ cnorm,                   // NN x 256
    const u16* __restrict__ P1t, const float* __restrict__ pb1,  // 64 x 256
    const u16* __restrict__ P2t, const float* __restrict__ pb2,  // 64 x 64
    const u16* __restrict__ node_in,                 // NN x 384 (cols 0..320 valid)
    const u16* __restrict__ N1t, const float* __restrict__ nb1,  // 64 x 384
    const u16* __restrict__ N2t, const float* __restrict__ nb2,  // 64 x 64
    const float* __restrict__ hres,
    float* __restrict__ hout,
    u16* __restrict__ hbf,
    u16* __restrict__ node_io){
  __shared__ u16 A_s[128*LP];
  __shared__ u16 B_s[64*LP];
  __shared__ u16 T_s[128*72];
  __shared__ u16 W2_s[64*72];
  __shared__ u16 HCm[128*72];   // h_comb
  const int tid = threadIdx.x, lane = tid & 63, wave = tid >> 6;
  const int m0 = blockIdx.x * 128;
  const int l15 = lane & 15, kq = (lane >> 4)*8;
  const int rsub = (lane >> 4) << 2;
  const int srow = tid >> 1, skh = (tid & 1)*16;
  const int arow = min(m0 + srow, NN - 1);
  const u16* aptr1 = cnorm + (size_t)arow*256 + skh;
  const u16* aptr2 = node_in + (size_t)arow*384 + skh;
  const int brow = tid >> 2, bcol = (tid & 3)*8;

  // stage pn W2^T
#pragma unroll
  for (int i = 0; i < 2; ++i){
    int idx = tid + i*256;
    int row = idx >> 3, cc = (idx & 7)*8;
    *reinterpret_cast<uint4*>(W2_s + row*72 + cc) =
        *reinterpret_cast<const uint4*>(P2t + row*64 + cc);
  }

  f32x4 acc0[4], acc1[4];
#pragma unroll
  for (int c = 0; c < 4; ++c){ acc0[c] = (f32x4){0,0,0,0}; acc1[c] = (f32x4){0,0,0,0}; }

  // pn GEMM1: K=256
  for (int kc = 0; kc < 256; kc += 32){
    *reinterpret_cast<uint4*>(A_s + srow*LP + skh)     = *reinterpret_cast<const uint4*>(aptr1 + kc);
    *reinterpret_cast<uint4*>(A_s + srow*LP + skh + 8) = *reinterpret_cast<const uint4*>(aptr1 + kc + 8);
    *reinterpret_cast<uint4*>(B_s + brow*LP + bcol) =
        *reinterpret_cast<const uint4*>(P1t + (size_t)brow*256 + kc + bcol);
    __syncthreads();
    bf16x8 af0 = *reinterpret_cast<const bf16x8*>(A_s + (wave*16 + l15)*LP + kq);
    bf16x8 af1 = *reinterpret_cast<const bf16x8*>(A_s + (64 + wave*16 + l15)*LP + kq);
#pragma unroll
    for (int c = 0; c < 4; ++c){
      bf16x8 bf = *reinterpret_cast<const bf16x8*>(B_s + (c*16 + l15)*LP + kq);
      acc0[c] = __builtin_amdgcn_mfma_f32_16x16x32_bf16(af0, bf, acc0[c], 0, 0, 0);
      acc1[c] = __builtin_amdgcn_mfma_f32_16x16x32_bf16(af1, bf, acc1[c], 0, 0, 0);
    }
    __syncthreads();
  }
  // epi1 -> T_s
#pragma unroll
  for (int h = 0; h < 2; ++h){
#pragma unroll
    for (int c = 0; c < 4; ++c){
      int n = c*16 + l15;
      float bb = pb1[n];
#pragma unroll
      for (int r = 0; r < 4; ++r){
        int rowloc = h*64 + wave*16 + rsub + r;
        float a = (h == 0) ? acc0[c][r] : acc1[c][r];
        T_s[rowloc*72 + n] = f2bf(siluf(a + bb));
      }
    }
  }
  __syncthreads();
  // pn GEMM2: K=64 -> h_comb -> HCm
#pragma unroll
  for (int c = 0; c < 4; ++c){ acc0[c] = (f32x4){0,0,0,0}; acc1[c] = (f32x4){0,0,0,0}; }
#pragma unroll
  for (int kc = 0; kc < 64; kc += 32){
    bf16x8 af0 = *reinterpret_cast<const bf16x8*>(T_s + (wave*16 + l15)*72 + kc + kq);
    bf16x8 af1 = *reinterpret_cast<const bf16x8*>(T_s + (64 + wave*16 + l15)*72 + kc + kq);
#pragma unroll
    for (int c = 0; c < 4; ++c){
      bf16x8 bf = *reinterpret_cast<const bf16x8*>(W2_s + (c*16 + l15)*72 + kc + kq);
      acc0[c] = __builtin_amdgcn_mfma_f32_16x16x32_bf16(af0, bf, acc0[c], 0, 0, 0);
      acc1[c] = __builtin_amdgcn_mfma_f32_16x16x32_bf16(af1, bf, acc1[c], 0, 0, 0);
    }
  }
#pragma unroll
  for (int h = 0; h < 2; ++h){
#pragma unroll
    for (int c = 0; c < 4; ++c){
      int n = c*16 + l15;
      float bb = pb2[n];
#pragma unroll
      for (int r = 0; r < 4; ++r){
        int rowloc = h*64 + wave*16 + rsub + r;
        float a = (h == 0) ? acc0[c][r] : acc1[c][r];
        HCm[rowloc*72 + n] = f2bf(siluf(a + bb));
      }
    }
  }
  __syncthreads();

  // node GEMM1: K=384 — cols 0..319 from global node_in, 320..383 from HCm
#pragma unroll
  for (int c = 0; c < 4; ++c){ acc0[c] = (f32x4){0,0,0,0}; acc1[c] = (f32x4){0,0,0,0}; }
  for (int kc = 0; kc < 320; kc += 32){
    *reinterpret_cast<uint4*>(A_s + srow*LP + skh)     = *reinterpret_cast<const uint4*>(aptr2 + kc);
    *reinterpret_cast<uint4*>(A_s + srow*LP + skh + 8) = *reinterpret_cast<const uint4*>(aptr2 + kc + 8);
    *reinterpret_cast<uint4*>(B_s + brow*LP + bcol) =
        *reinterpret_cast<const uint4*>(N1t + (size_t)brow*384 + kc + bcol);
    __syncthreads();
    bf16x8 af0 = *reinterpret_cast<const bf16x8*>(A_s + (wave*16 + l15)*LP + kq);
    bf16x8 af1 = *reinterpret_cast<const bf16x8*>(A_s + (64 + wave*16 + l15)*LP + kq);
#pragma unroll
    for (int c = 0; c < 4; ++c){
      bf16x8 bf = *reinterpret_cast<const bf16x8*>(B_s + (c*16 + l15)*LP + kq);
      acc0[c] = __builtin_amdgcn_mfma_f32_16x16x32_bf16(af0, bf, acc0[c], 0, 0, 0);
      acc1[c] = __builtin_amdgcn_mfma_f32_16x16x32_bf16(af1, bf, acc1[c], 0, 0, 0);
    }
    __syncthreads();
  }
#pragma unroll
  for (int kc = 320; kc < 384; kc += 32){
    bf16x8 af0 = *reinterpret_cast<const bf16x8*>(HCm + (wave*16 + l15)*72 + (kc-320) + kq);
    bf16x8 af1 = *reinterpret_cast<const bf16x8*>(HCm + (64 + wave*16 + l15)*72 + (kc-320) + kq);
#pragma unroll
    for (int c = 0; c < 4; ++c){
      bf16x8 bf = ldg_bf8(N1t + (size_t)(c*16 + l15)*384 + kc + kq);
      acc0[c] = __builtin_amdgcn_mfma_f32_16x16x32_bf16(af0, bf, acc0[c], 0, 0, 0);
      acc1[c] = __builtin_amdgcn_mfma_f32_16x16x32_bf16(af1, bf, acc1[c], 0, 0, 0);
    }
  }
  // epi1 -> T_s + stage node W2^T
#pragma unroll
  for (int h = 0; h < 2; ++h){
#pragma unroll
    for (int c = 0; c < 4; ++c){
      int n = c*16 + l15;
      float bb = nb1[n];
#pragma unroll
      for (int r = 0; r < 4; ++r){
        int rowloc = h*64 + wave*16 + rsub + r;
        float a = (h == 0) ? acc0[c][r] : acc1[c][r];
        T_s[rowloc*72 + n] = f2bf(siluf(a + bb));
      }
    }
  }
#pragma unroll
  for (int i = 0; i < 2; ++i){
    int idx = tid + i*256;
    int row = idx >> 3, cc = (idx & 7)*8;
    *reinterpret_cast<uint4*>(W2_s + row*72 + cc) =
        *reinterpret_cast<const uint4*>(N2t + row*64 + cc);
  }
  __syncthreads();
  // node GEMM2: K=64
#pragma unroll
  for (int c = 0; c < 4; ++c){ acc0[c] = (f32x4){0,0,0,0}; acc1[c] = (f32x4){0,0,0,0}; }
#pragma unroll
  for (int kc = 0; kc < 64; kc += 32){
    bf16x8 af0 = *reinterpret_cast<const bf16x8*>(T_s + (wave*16 + l15)*72 + kc + kq);
    bf16x8 af1 = *reinterpret_cast<const bf16x8*>(T_s + (64 + wave*16 + l15)*72 + kc + kq);
#pragma unroll
    for (int c = 0; c < 4; ++c){
      bf16x8 bf = *reinterpret_cast<const bf16x8*>(W2_s + (c*16 + l15)*72 + kc + kq);
      acc0[c] = __builtin_amdgcn_mfma_f32_16x16x32_bf16(af0, bf, acc0[c], 0, 0, 0);
      acc1[c] = __builtin_amdgcn_mfma_f32_16x16x32_bf16(af1, bf, acc1[c], 0, 0, 0);
    }
  }
  // epi: h' = h + silu(.)
#pragma unroll
  for (int h = 0; h < 2; ++h){
#pragma unroll
    for (int c = 0; c < 4; ++c){
      int n = c*16 + l15;
      float bb = nb2[n];
#pragma unroll
      for (int r = 0; r < 4; ++r){
        int m = m0 + h*64 + wave*16 + rsub + r;
        if (m >= NN) continue;
        float a = (h == 0) ? acc0[c][r] : acc1[c][r];
        float hn = hres[(size_t)m*64 + n] + siluf(a + bb);
        hout[(size_t)m*64 + n] = hn;
        u16 bbf = f2bf(hn);
        hbf[(size_t)m*64 + n] = bbf;
        node_io[(size_t)m*384 + n] = bbf;
      }
    }
  }
}

// ==== 2-layer MLP (epilogue head): fp32 out = silu(A@W1+b1)@W2 + b2 ====
__global__ __launch_bounds__(256) void mlp2_head_k(const u16* __restrict__ A,
                                                   const u16* __restrict__ W1t,
                                                   const float* __restrict__ b1,
                                                   const u16* __restrict__ W2t,
                                                   const float* __restrict__ b2,
                                                   float* __restrict__ outf){
  __shared__ u16 A_s[128*LP];
  __shared__ u16 B_s[64*LP];
  __shared__ u16 T_s[128*72];
  __shared__ u16 W2_s[64*72];
  const int tid = threadIdx.x, lane = tid & 63, wave = tid >> 6;
  const int m0 = blockIdx.x * 128;
  const int l15 = lane & 15, kq = (lane >> 4)*8;
  const int rsub = (lane >> 4) << 2;
#pragma unroll
  for (int i = 0; i < 2; ++i){
    int idx = tid + i*256;
    int row = idx >> 3, cc = (idx & 7)*8;
    *reinterpret_cast<uint4*>(W2_s + row*72 + cc) =
        *reinterpret_cast<const uint4*>(W2t + row*64 + cc);
  }
  const int srow = tid >> 1, skh = (tid & 1)*16;
  const int arow = min(m0 + srow, NN - 1);
  const u16* aptr = A + (size_t)arow*64 + skh;

  f32x4 acc0[4], acc1[4];
#pragma unroll
  for (int c = 0; c < 4; ++c){ acc0[c] = (f32x4){0,0,0,0}; acc1[c] = (f32x4){0,0,0,0}; }
  const int brow = tid >> 2, bcol = (tid & 3)*8;
  for (int kc = 0; kc < 64; kc += 32){
    *reinterpret_cast<uint4*>(A_s + srow*LP + skh)     = *reinterpret_cast<const uint4*>(aptr + kc);
    *reinterpret_cast<uint4*>(A_s + srow*LP + skh + 8) = *reinterpret_cast<const uint4*>(aptr + kc + 8);
    *reinterpret_cast<uint4*>(B_s + brow*LP + bcol) =
        *reinterpret_cast<const uint4*>(W1t + (size_t)brow*64 + kc + bcol);
    __syncthreads();
    bf16x8 af0 = *reinterpret_cast<const bf16x8*>(A_s + (wave*16 + l15)*LP + kq);
    bf16x8 af1 = *reinterpret_cast<const bf16x8*>(A_s + (64 + wave*16 + l15)*LP + kq);
#pragma unroll
    for (int c = 0; c < 4; ++c){
      bf16x8 bf = *reinterpret_cast<const bf16x8*>(B_s + (c*16 + l15)*LP + kq);
      acc0[c] = __builtin_amdgcn_mfma_f32_16x16x32_bf16(af0, bf, acc0[c], 0, 0, 0);
      acc1[c] = __builtin_amdgcn_mfma_f32_16x16x32_bf16(af1, bf, acc1[c], 0, 0, 0);
    }
    __syncthreads();
  }
#pragma unroll
  for (int h = 0; h < 2; ++h){
#pragma unroll
    for (int c = 0; c < 4; ++c){
      int n = c*16 + l15;
      float bb = b1[n];
#pragma unroll
      for (int r = 0; r < 4; ++r){
        int rowloc = h*64 + wave*16 + rsub + r;
        float a = (h == 0) ? acc0[c][r] : acc1[c][r];
        T_s[rowloc*72 + n] = f2bf(siluf(a + bb));
      }
    }
  }
  __syncthreads();
#pragma unroll
  for (int c = 0; c < 4; ++c){ acc0[c] = (f32x4){0,0,0,0}; acc1[c] = (f32x4){0,0,0,0}; }
#pragma unroll
  for (int kc = 0; kc < 64; kc += 32){
    bf16x8 af0 = *reinterpret_cast<const bf16x8*>(T_s + (wave*16 + l15)*72 + kc + kq);
    bf16x8 af1 = *reinterpret_cast<const bf16x8*>(T_s + (64 + wave*16 + l15)*72 + kc + kq);
#pragma unroll
    for (int c = 0; c < 4; ++c){
      bf16x8 bf = *reinterpret_cast<const bf16x8*>(W2_s + (c*16 + l15)*72 + kc + kq);
      acc0[c] = __builtin_amdgcn_mfma_f32_16x16x32_bf16(af0, bf, acc0[c], 0, 0, 0);
      acc1[c] = __builtin_amdgcn_mfma_f32_16x16x32_bf16(af1, bf, acc1[c], 0, 0, 0);
    }
  }
#pragma unroll
  for (int h = 0; h < 2; ++h){
#pragma unroll
    for (int c = 0; c < 4; ++c){
      int n = c*16 + l15;
      float bb = b2[n];
#pragma unroll
      for (int r = 0; r < 4; ++r){
        int m = m0 + h*64 + wave*16 + rsub + r;
        if (m >= NN) continue;
        float a = (h == 0) ? acc0[c][r] : acc1[c][r];
        outf[(size_t)m*64 + n] = a + bb;
      }
    }
  }
}

// ---- generic tiled fp32 GEMM (small cases) ----
template<int EPI>
__global__ __launch_bounds__(256) void gemm_k(const float* __restrict__ A, int lda,
                                              const float* __restrict__ W, int ldw,
                                              const float* __restrict__ bias,
                                              float* __restrict__ out, int ldo, int ocol,
                                              int M, int N, int K){
  __shared__ float w_s[128*64];
  const int tid  = threadIdx.x;
  const int nl   = tid & 63;
  const int rg   = tid >> 6;
  const int col0 = blockIdx.y * 64;
  const int m0   = blockIdx.x * 16 + rg * 4;
  float acc[4] = {0.f, 0.f, 0.f, 0.f};
  const float* ar[4];
#pragma unroll
  for (int r = 0; r < 4; ++r){
    int mr = min(m0 + r, M - 1);
    ar[r] = A + (size_t)mr * lda;
  }
  for (int kc = 0; kc < K; kc += 128){
    int kn = min(128, K - kc);
    for (int idx = tid; idx < 128*64; idx += 256){
      int kk = idx >> 6, nn = idx & 63;
      int gn = col0 + nn;
      w_s[idx] = (kk < kn && gn < N) ? W[(size_t)(kc+kk)*ldw + gn] : 0.f;
    }
    __syncthreads();
    for (int k = 0; k < kn; ++k){
      float wv = w_s[k*64 + nl];
#pragma unroll
      for (int r = 0; r < 4; ++r) acc[r] = fmaf(ar[r][kc + k], wv, acc[r]);
    }
    __syncthreads();
  }
  int n = col0 + nl;
  if (n >= N) return;
  float b = bias ? bias[n] : 0.f;
#pragma unroll
  for (int r = 0; r < 4; ++r){
    int m = m0 + r;
    if (m >= M) break;
    float a = acc[r] + b;
    out[(size_t)m*ldo + ocol + n] = (EPI == 1) ? siluf(a) : a;
  }
}

// ---- per-node attention over contiguous CSR segment ----
__global__ __launch_bounds__(256) void att_k(const int* __restrict__ offs,
                                             const float* __restrict__ dS,
                                             const float* __restrict__ logit,
                                             float* __restrict__ att){
  int lane = threadIdx.x & 63;
  int node = (blockIdx.x * 256 + threadIdx.x) >> 6;
  if (node >= NN) return;
  int s0 = offs[node];
  int cnt = offs[node+1] - s0;
  if (cnt <= 0) return;
  const float NEG = -1e30f;
  if (cnt <= 64){
    bool act = lane < cnt;
    int p = s0 + (act ? lane : 0);
    float dd = dS[p];
    float4 lg = *reinterpret_cast<const float4*>(logit + 4*(size_t)p);
    float me  = wred_max(act ? -dd  : NEG);
    float ms0 = wred_max(act ? lg.x : NEG);
    float ms1 = wred_max(act ? lg.y : NEG);
    float ms2 = wred_max(act ? lg.z : NEG);
    float ms3 = wred_max(act ? lg.w : NEG);
    float ee  = act ? __expf(-dd - me)  : 0.f;
    float v0  = act ? __expf(lg.x - ms0) : 0.f;
    float v1  = act ? __expf(lg.y - ms1) : 0.f;
    float v2  = act ? __expf(lg.z - ms2) : 0.f;
    float v3  = act ? __expf(lg.w - ms3) : 0.f;
    float ise = 1.f / wred_sum(ee);
    float is0 = 1.f / wred_sum(v0);
    float is1 = 1.f / wred_sum(v1);
    float is2 = 1.f / wred_sum(v2);
    float is3 = 1.f / wred_sum(v3);
    float ae = ee * ise;
    float a0 = ae * v0 * is0, a1 = ae * v1 * is1;
    float a2 = ae * v2 * is2, a3 = ae * v3 * is3;
    float iz0 = 1.f / wred_sum(a0), iz1 = 1.f / wred_sum(a1);
    float iz2 = 1.f / wred_sum(a2), iz3 = 1.f / wred_sum(a3);
    if (act){
      float4 o; o.x = a0*iz0; o.y = a1*iz1; o.z = a2*iz2; o.w = a3*iz3;
      *reinterpret_cast<float4*>(att + 4*(size_t)p) = o;
    }
    return;
  }
  float me = NEG, ms0 = NEG, ms1 = NEG, ms2 = NEG, ms3 = NEG;
  for (int j = lane; j < cnt; j += 64){
    int p = s0 + j;
    float dd = dS[p];
    me = fmaxf(me, -dd);
    float4 lg = *reinterpret_cast<const float4*>(logit + 4*(size_t)p);
    ms0 = fmaxf(ms0, lg.x); ms1 = fmaxf(ms1, lg.y);
    ms2 = fmaxf(ms2, lg.z); ms3 = fmaxf(ms3, lg.w);
  }
  me = wred_max(me); ms0 = wred_max(ms0); ms1 = wred_max(ms1);
  ms2 = wred_max(ms2); ms3 = wred_max(ms3);
  float se = 0.f, ss0 = 0.f, ss1 = 0.f, ss2 = 0.f, ss3 = 0.f;
  for (int j = lane; j < cnt; j += 64){
    int p = s0 + j;
    float dd = dS[p];
    float4 lg = *reinterpret_cast<const float4*>(logit + 4*(size_t)p);
    se  += __expf(-dd - me);
    ss0 += __expf(lg.x - ms0); ss1 += __expf(lg.y - ms1);
    ss2 += __expf(lg.z - ms2); ss3 += __expf(lg.w - ms3);
  }
  se = wred_sum(se); ss0 = wred_sum(ss0); ss1 = wred_sum(ss1);
  ss2 = wred_sum(ss2); ss3 = wred_sum(ss3);
  float ise = 1.f/se, is0 = 1.f/ss0, is1 = 1.f/ss1, is2 = 1.f/ss2, is3 = 1.f/ss3;
  float z0 = 0.f, z1 = 0.f, z2 = 0.f, z3 = 0.f;
  for (int j = lane; j < cnt; j += 64){
    int p = s0 + j;
    float dd = dS[p];
    float4 lg = *reinterpret_cast<const float4*>(logit + 4*(size_t)p);
    float ae = __expf(-dd - me) * ise;
    z0 += ae * __expf(lg.x - ms0) * is0;
    z1 += ae * __expf(lg.y - ms1) * is1;
    z2 += ae * __expf(lg.z - ms2) * is2;
    z3 += ae * __expf(lg.w - ms3) * is3;
  }
  z0 = wred_sum(z0); z1 = wred_sum(z1); z2 = wred_sum(z2); z3 = wred_sum(z3);
  float iz0 = 1.f/z0, iz1 = 1.f/z1, iz2 = 1.f/z2, iz3 = 1.f/z3;
  for (int j = lane; j < cnt; j += 64){
    int p = s0 + j;
    float dd = dS[p];
    float4 lg = *reinterpret_cast<const float4*>(logit + 4*(size_t)p);
    float ae = __expf(-dd - me) * ise;
    float4 o;
    o.x = ae * __expf(lg.x - ms0) * is0 * iz0;
    o.y = ae * __expf(lg.y - ms1) * is1 * iz1;
    o.z = ae * __expf(lg.z - ms2) * is2 * iz2;
    o.w = ae * __expf(lg.w - ms3) * is3 * iz3;
    *reinterpret_cast<float4*>(att + 4*(size_t)p) = o;
  }
}

// ---- per-node aggregate (contiguous CSR), 2x unrolled; applies tanh to raw coef ----
__global__ __launch_bounds__(256) void agg_k(const int* __restrict__ offs,
                                             const u16* __restrict__ coef,
                                             const u16* __restrict__ he,
                                             const float* __restrict__ att,
                                             const float* __restrict__ dirsS,
                                             u16* __restrict__ cnorm,
                                             u16* __restrict__ node_in){
  int node = blockIdx.x;
  int c = threadIdx.x;
  int s0 = offs[node], s1 = offs[node+1];
  int q = c >> 2, hd = c & 3;
  float cs0 = 0.f, cs1 = 0.f, cs2 = 0.f, ha = 0.f;
  int p = s0;
  for (; p + 2 <= s1; p += 2){
    float co0 = fast_tanh(bf2f(coef[(size_t)p*256 + c]));
    float co1 = fast_tanh(bf2f(coef[(size_t)(p+1)*256 + c]));
    float hv0 = bf2f(he[(size_t)p*64 + q]);
    float hv1 = bf2f(he[(size_t)(p+1)*64 + q]);
    float av0 = att[(size_t)p*4 + hd];
    float av1 = att[(size_t)(p+1)*4 + hd];
    float d00 = dirsS[3*(size_t)p],     d01 = dirsS[3*(size_t)p+1],     d02 = dirsS[3*(size_t)p+2];
    float d10 = dirsS[3*(size_t)(p+1)], d11 = dirsS[3*(size_t)(p+1)+1], d12 = dirsS[3*(size_t)(p+1)+2];
    cs0 = fmaf(co0, d00, cs0); cs1 = fmaf(co0, d01, cs1); cs2 = fmaf(co0, d02, cs2);
    cs0 = fmaf(co1, d10, cs0); cs1 = fmaf(co1, d11, cs1); cs2 = fmaf(co1, d12, cs2);
    ha = fmaf(hv0, av0, ha);
    ha = fmaf(hv1, av1, ha);
  }
  if (p < s1){
    float co = fast_tanh(bf2f(coef[(size_t)p*256 + c]));
    float hv = bf2f(he[(size_t)p*64 + q]);
    float av = att[(size_t)p*4 + hd];
    float d0 = dirsS[3*(size_t)p], d1 = dirsS[3*(size_t)p+1], d2 = dirsS[3*(size_t)p+2];
    cs0 = fmaf(co, d0, cs0); cs1 = fmaf(co, d1, cs1); cs2 = fmaf(co, d2, cs2);
    ha = fmaf(hv, av, ha);
  }
  cnorm[(size_t)node*256 + c] = f2bf(cs0*cs0 + cs1*cs1 + cs2*cs2);
  node_in[(size_t)node*384 + 64 + c] = f2bf(ha);
}

// ---- graph pooling ----
__global__ __launch_bounds__(256) void segy_k(const float* __restrict__ hf,
                                              const int* __restrict__ seg,
                                              float* __restrict__ y){
  int gid = blockIdx.x * 256 + threadIdx.x;
  if (gid >= NN*64) return;
  int n = gid >> 6, ch = gid & 63;
  atomicAdd(&y[seg[n]*64 + ch], hf[gid]);
}

// ---- final head ----
__global__ void headf_k(const float* __restrict__ t2,
                        const float* __restrict__ w2,
                        const float* __restrict__ b2,
                        float* __restrict__ out){
  int s = threadIdx.x;
  if (s >= NSEG) return;
  float acc = b2[0];
  for (int k = 0; k < 64; ++k) acc = fmaf(t2[s*64 + k], w2[k], acc);
  out[s] = acc;
}

extern "C" void kernel_launch(void* const* d_in, const int* in_sizes, int n_in,
                              void* d_out, int out_size, void* d_ws, size_t ws_size,
                              hipStream_t stream) {
  (void)in_sizes; (void)n_in; (void)out_size; (void)ws_size;
  const float* in_i       = (const float*)d_in[0];
  const float* in_x       = (const float*)d_in[1];
  const float* emb_in_w   = (const float*)d_in[2];
  const float* emb_in_b   = (const float*)d_in[3];
  const float* edge_in_w  = (const float*)d_in[4];
  const float* edge_in_b  = (const float*)d_in[5];
  const float* rbf_means  = (const float*)d_in[6];
  const float* rbf_betas  = (const float*)d_in[7];
  const float* edge_o_w1  = (const float*)d_in[8];
  const float* edge_o_b1  = (const float*)d_in[9];
  const float* edge_o_w2  = (const float*)d_in[10];
  const float* edge_o_b2  = (const float*)d_in[11];
  const float* sem_w      = (const float*)d_in[12];
  const float* sem_b      = (const float*)d_in[13];
  const float* xmix_w     = (const float*)d_in[14];
  const float* pn_w1      = (const float*)d_in[15];
  const float* pn_b1      = (const float*)d_in[16];
  const float* pn_w2      = (const float*)d_in[17];
  const float* pn_b2      = (const float*)d_in[18];
  const float* node_w1    = (const float*)d_in[19];
  const float* node_b1    = (const float*)d_in[20];
  const float* node_w2    = (const float*)d_in[21];
  const float* node_b2    = (const float*)d_in[22];
  const float* emb_o_w1   = (const float*)d_in[23];
  const float* emb_o_b1   = (const float*)d_in[24];
  const float* emb_o_w2   = (const float*)d_in[25];
  const float* emb_o_b2   = (const float*)d_in[26];
  const float* head_w1    = (const float*)d_in[27];
  const float* head_b1    = (const float*)d_in[28];
  const float* head_w2    = (const float*)d_in[29];
  const float* head_b2    = (const float*)d_in[30];
  const int*   edges      = (const int*)d_in[31];
  const int*   segs       = (const int*)d_in[32];
  float* out = (float*)d_out;

  // workspace carve-up (256B aligned)
  char* base = (char*)d_ws;
  size_t off = 0;
  auto alloc = [&](size_t bytes) -> void* {
    void* p = base + off;
    off += (bytes + 255) & ~(size_t)255;
    return p;
  };
  float* dS     = (float*)alloc((size_t)EN*4);
  float* dirsS  = (float*)alloc((size_t)EN*3*4);
  float* rbfS   = (float*)alloc((size_t)EN*4);
  int*   edge_s = (int*)alloc((size_t)EN*2*4);
  float* hA     = (float*)alloc((size_t)NN*64*4);
  float* hB     = (float*)alloc((size_t)NN*64*4);
  u16*   he     = (u16*)alloc((size_t)EN*64*2);
  u16*   coef   = (u16*)alloc((size_t)EN*256*2);
  float* logit  = (float*)alloc((size_t)EN*4*4);
  float* att    = (float*)alloc((size_t)EN*4*4);
  u16*   hbf    = (u16*)alloc((size_t)NN*64*2);
  u16*   node_in= (u16*)alloc((size_t)NN*384*2);
  u16*   cnorm  = (u16*)alloc((size_t)NN*256*2);
  float* y      = (float*)alloc((size_t)NSEG*64*4);
  float* t2     = (float*)alloc((size_t)NSEG*64*4);
  u16* winb  = (u16*)alloc((size_t)DEPTH*64*128*2);
  u16* w1b   = (u16*)alloc((size_t)DEPTH*64*192*2);
  u16* w2b   = (u16*)alloc((size_t)DEPTH*64*64*2);
  u16* xr    = (u16*)alloc((size_t)DEPTH*4*256*64*2);   // [l][hd][n][q]
  u16* pw1b  = (u16*)alloc((size_t)DEPTH*64*256*2);
  u16* pw2b  = (u16*)alloc((size_t)DEPTH*64*64*2);
  u16* nw1b  = (u16*)alloc((size_t)DEPTH*64*384*2);
  u16* nw2b  = (u16*)alloc((size_t)DEPTH*64*64*2);
  u16* eo1b  = (u16*)alloc((size_t)64*64*2);
  u16* eo2b  = (u16*)alloc((size_t)64*64*2);
  int* counts   = (int*)alloc((size_t)NN*4);
  int* cursor   = (int*)alloc((size_t)NN*4);
  int* offs     = (int*)alloc((size_t)(NN+1)*4);

  hipMemsetAsync(counts, 0, (size_t)NN*4, stream);
  hipMemsetAsync(cursor, 0, (size_t)NN*4, stream);
  hipMemsetAsync(y, 0, (size_t)NSEG*64*4, stream);

  count_k<<<(EN+255)/256, 256, 0, stream>>>(edges, counts);
  scan_k<<<1, 256, 0, stream>>>(counts, offs);
  geoscat_k<<<(EN+255)/256, 256, 0, stream>>>(edges, in_x, offs, cursor,
                                              edge_s, dS, dirsS, rbfS);

  // weight conversions (once per call)
  convw_k<<<dim3(32,  DEPTH), 256, 0, stream>>>(edge_in_w, 128, 50, (size_t)128*50, winb, 128, 64, (size_t)64*128);
  convw_k<<<dim3(48,  DEPTH), 256, 0, stream>>>(edge_o_w1, 179, 64, (size_t)179*64, w1b,  192, 64, (size_t)64*192);
  convw_k<<<dim3(16,  DEPTH), 256, 0, stream>>>(edge_o_w2,  64, 64, (size_t)64*64,  w2b,   64, 64, (size_t)64*64);
  convx_k<<<dim3(256, DEPTH), 256, 0, stream>>>(xmix_w, xr);
  convw_k<<<dim3(64,  DEPTH), 256, 0, stream>>>(pn_w1,     256, 64, (size_t)256*64, pw1b, 256, 64, (size_t)64*256);
  convw_k<<<dim3(16,  DEPTH), 256, 0, stream>>>(pn_w2,      64, 64, (size_t)64*64,  pw2b,  64, 64, (size_t)64*64);
  convw_k<<<dim3(96,  DEPTH), 256, 0, stream>>>(node_w1,   384, 64, (size_t)384*64, nw1b, 384, 64, (size_t)64*384);
  convw_k<<<dim3(16,  DEPTH), 256, 0, stream>>>(node_w2,    64, 64, (size_t)64*64,  nw2b,  64, 64, (size_t)64*64);
  convw_k<<<dim3(16,  1),     256, 0, stream>>>(emb_o_w1,   64, 64, (size_t)64*64,  eo1b,  64, 64, (size_t)64*64);
  convw_k<<<dim3(16,  1),     256, 0, stream>>>(emb_o_w2,   64, 64, (size_t)64*64,  eo2b,  64, 64, (size_t)64*64);

  // h = i @ emb_in_w + b   (fp32, K=16)
  gemm_k<0><<<dim3((NN+15)/16, 1), 256, 0, stream>>>(
      in_i, 16, emb_in_w, 64, emb_in_b, hA, 64, 0, NN, 64, 16);
  h2b_k<<<(NN*64)/256, 256, 0, stream>>>(hA, hbf, node_in);

  const int EB  = (EN + 63) / 64;     // 1563 edge tiles
  const int EB2 = (EN + 127) / 128;   // 782
  const int NB2 = (NN + 127) / 128;   // 79

  float* hcur = hA;
  float* hnext = hB;
  for (int l = 0; l < DEPTH; ++l){
    const float* bin  = edge_in_b + (size_t)l*50;
    const float* mean = rbf_means + (size_t)l*50;
    const float* beta = rbf_betas + (size_t)l*50;
    const float* b1   = edge_o_b1 + (size_t)l*64;
    const float* b2   = edge_o_b2 + (size_t)l*64;
    const float* sw   = sem_w + (size_t)l*64*4;
    const float* sb   = sem_b + (size_t)l*4;
    const float* pb1  = pn_b1 + (size_t)l*64;
    const float* pb2  = pn_b2 + (size_t)l*64;
    const float* nb1  = node_b1 + (size_t)l*64;
    const float* nb2  = node_b2 + (size_t)l*64;
    const u16* Winb = winb + (size_t)l*64*128;
    const u16* W1b  = w1b  + (size_t)l*64*192;
    const u16* W2b  = w2b  + (size_t)l*64*64;
    const u16* Xrl  = xr   + (size_t)l*65536;
    const u16* P1b  = pw1b + (size_t)l*64*256;
    const u16* P2b  = pw2b + (size_t)l*64*64;
    const u16* N1b  = nw1b + (size_t)l*64*384;
    const u16* N2b  = nw2b + (size_t)l*64*64;

    edge_fused_k<<<EB, 256, 0, stream>>>(edge_s, hbf, rbfS, dS,
                                         Winb, bin, mean, beta,
                                         W1b, b1, W2b, b2, sw, sb,
                                         he, logit);
    att_k<<<(NN+3)/4, 256, 0, stream>>>(offs, dS, logit, att);
    xmix_k<<<EB2, 256, 0, stream>>>(he, att, Xrl, coef);
    agg_k<<<NN, 256, 0, stream>>>(offs, coef, he, att, dirsS, cnorm, node_in);
    nodeblock_k<<<NB2, 256, 0, stream>>>(cnorm, P1b, pb1, P2b, pb2,
                                         node_in, N1b, nb1, N2b, nb2,
                                         hcur, hnext, hbf, node_in);
    float* tmp = hcur; hcur = hnext; hnext = tmp;
  }

  // output head: hnext = silu(hbf@eo1+b1)@eo2+b2  (bf16 MFMA, fp32 out)
  mlp2_head_k<<<NB2, 256, 0, stream>>>(hbf, eo1b, emb_o_b1, eo2b, emb_o_b2, hnext);
  segy_k<<<(NN*64)/256, 256, 0, stream>>>(hnext, segs, y);
  gemm_k<1><<<dim3((NSEG+15)/16, 1), 256, 0, stream>>>(
      y, 64, head_w1, 64, head_b1, t2, 64, 0, NSEG, 64, 64);
  headf_k<<<1, 128, 0, stream>>>(t2, head_w2, head_b2, out);
}